// Round 1
// 2916.525 us; speedup vs baseline: 1.0227x; 1.0227x over previous
//
#include <hip/hip_runtime.h>
#include <math.h>

// ---- problem constants ----
constexpr int DIMC   = 768;
constexpr int NHEADS = 12;
constexpr int HD     = 64;
constexpr int NCLS   = 20;
constexpr int HID    = 3072;
constexpr int NBATCH = 16;
constexpr int NSEQ   = 596;
constexpr int NT     = NBATCH * NSEQ;   // 9536 tokens
constexpr int C3     = 3 * DIMC;        // 2304
#define LN_EPS 1e-5f

// ============================================================
// LayerNorm: one block (256 thr) per row of 768
// ============================================================
__global__ __launch_bounds__(256) void ln_kernel(const float* __restrict__ x,
                                                 const float* __restrict__ g,
                                                 const float* __restrict__ b,
                                                 float* __restrict__ y) {
    const int row = blockIdx.x;
    const float* xr = x + (size_t)row * DIMC;
    const int t = threadIdx.x;
    float v0 = xr[t];
    float v1 = xr[t + 256];
    float v2 = xr[t + 512];
    float s  = v0 + v1 + v2;
    float ss = v0 * v0 + v1 * v1 + v2 * v2;
#pragma unroll
    for (int m = 1; m < 64; m <<= 1) {
        s  += __shfl_xor(s, m);
        ss += __shfl_xor(ss, m);
    }
    __shared__ float ls[4], lss[4];
    const int wid = t >> 6;
    if ((t & 63) == 0) { ls[wid] = s; lss[wid] = ss; }
    __syncthreads();
    s  = ls[0] + ls[1] + ls[2] + ls[3];
    ss = lss[0] + lss[1] + lss[2] + lss[3];
    const float mean = s * (1.0f / DIMC);
    const float var  = ss * (1.0f / DIMC) - mean * mean;
    const float rstd = rsqrtf(var + LN_EPS);
    float* yr = y + (size_t)row * DIMC;
    int c = t;
    yr[c] = (v0 - mean) * rstd * g[c] + b[c];
    c += 256;
    yr[c] = (v1 - mean) * rstd * g[c] + b[c];
    c += 256;
    yr[c] = (v2 - mean) * rstd * g[c] + b[c];
}

// ============================================================
// GEMM: Out[M,Nn] = A[M,K] @ W[Nn,K]^T + bias (+res | gelu)
// 128x128 tile, BK=16, 256 threads, 8x8 micro-tile.
// EPI: 0 = bias, 1 = bias+residual, 2 = bias+GELU(exact)
// Requires: Nn % 128 == 0, K % 16 == 0. M guarded.
// ============================================================
__device__ __forceinline__ float gelu_f(float v) {
    return 0.5f * v * (1.0f + erff(v * 0.70710678118654752f));
}

template <int EPI>
__global__ __launch_bounds__(256) void gemm_kernel(const float* __restrict__ A,
                                                   const float* __restrict__ W,
                                                   const float* __restrict__ bias,
                                                   const float* __restrict__ res,
                                                   float* __restrict__ Out,
                                                   int M, int Nn, int K) {
    constexpr int BM = 128, BN = 128, BK = 16;
    constexpr int LDT = 132;  // padded LDS stride (words); 132*4 B = 16B-aligned rows
    __shared__ float As[BK][LDT];
    __shared__ float Ws[BK][LDT];

    const int tid = threadIdx.x;
    const int tx = tid & 15, ty = tid >> 4;
    const int m0 = blockIdx.y * BM;
    const int n0 = blockIdx.x * BN;

    float acc[8][8];
#pragma unroll
    for (int i = 0; i < 8; i++)
#pragma unroll
        for (int j = 0; j < 8; j++) acc[i][j] = 0.f;

    for (int kt = 0; kt < K; kt += BK) {
        // stage A and W tiles: 128 rows x 16 k each = 512 float4 per tile, 2/thread
#pragma unroll
        for (int l = 0; l < 2; l++) {
            const int fl  = tid + l * 256;
            const int row = fl >> 2, k4 = fl & 3;
            const int gm = m0 + row;
            float4 va = make_float4(0.f, 0.f, 0.f, 0.f);
            if (gm < M) va = *(const float4*)(A + (size_t)gm * K + kt + k4 * 4);
            As[k4 * 4 + 0][row] = va.x;
            As[k4 * 4 + 1][row] = va.y;
            As[k4 * 4 + 2][row] = va.z;
            As[k4 * 4 + 3][row] = va.w;
            const int gn = n0 + row;  // Nn % 128 == 0 -> always in bounds
            const float4 vw = *(const float4*)(W + (size_t)gn * K + kt + k4 * 4);
            Ws[k4 * 4 + 0][row] = vw.x;
            Ws[k4 * 4 + 1][row] = vw.y;
            Ws[k4 * 4 + 2][row] = vw.z;
            Ws[k4 * 4 + 3][row] = vw.w;
        }
        __syncthreads();
#pragma unroll
        for (int k = 0; k < BK; k++) {
            float a[8], w[8];
            *(float4*)&a[0] = *(const float4*)&As[k][ty * 8];
            *(float4*)&a[4] = *(const float4*)&As[k][ty * 8 + 4];
            *(float4*)&w[0] = *(const float4*)&Ws[k][tx * 8];
            *(float4*)&w[4] = *(const float4*)&Ws[k][tx * 8 + 4];
#pragma unroll
            for (int i = 0; i < 8; i++)
#pragma unroll
                for (int j = 0; j < 8; j++) acc[i][j] = fmaf(a[i], w[j], acc[i][j]);
        }
        __syncthreads();
    }

    // epilogue
#pragma unroll
    for (int i = 0; i < 8; i++) {
        const int gm = m0 + ty * 8 + i;
        if (gm < M) {
            const size_t off = (size_t)gm * Nn + n0 + tx * 8;
#pragma unroll
            for (int jv = 0; jv < 2; jv++) {
                float4 v;
                v.x = acc[i][jv * 4 + 0] + bias[n0 + tx * 8 + jv * 4 + 0];
                v.y = acc[i][jv * 4 + 1] + bias[n0 + tx * 8 + jv * 4 + 1];
                v.z = acc[i][jv * 4 + 2] + bias[n0 + tx * 8 + jv * 4 + 2];
                v.w = acc[i][jv * 4 + 3] + bias[n0 + tx * 8 + jv * 4 + 3];
                if (EPI == 1) {
                    const float4 rr = *(const float4*)(res + off + jv * 4);
                    v.x += rr.x; v.y += rr.y; v.z += rr.z; v.w += rr.w;
                } else if (EPI == 2) {
                    v.x = gelu_f(v.x); v.y = gelu_f(v.y);
                    v.z = gelu_f(v.z); v.w = gelu_f(v.w);
                }
                *(float4*)(Out + off + jv * 4) = v;
            }
        }
    }
}

// ============================================================
// Attention pass A (v3): scores in REGISTERS + swizzled K tile.
// One block = 16 q-rows x all 596 keys for one (b,h).
// Thread (ty,tx): q-row ty, keys {64*ch + 4*tx + j}, j=0..3 -> p[10][4] regs.
// Ks is [64][64] with the d-chunk index XOR-swizzled by (row>>2) so the
// inner-loop read bank = 4*((d4^tx) mod 8): 8 bank-groups x 2 addrs = free
// (was: LDK=68 -> 2 bank-groups x 8 addrs = 8-way conflict, ~50% of cycles).
// No S LDS buffer: softmax runs on registers + width-16 shfl reductions.
// LDS 63KB -> 20.7KB, occupancy becomes VGPR-limited.
// ============================================================
__global__ __launch_bounds__(256) void attn_scores_kernel(const float* __restrict__ qkv,
                                                          float* __restrict__ wts) {
    constexpr int TQ = 16, CHK = 64, NCH = 10;
    __shared__ float Qs[TQ][68];    //  4,352 B (stride 68 words: rows 16B-aligned, banks spread by ty)
    __shared__ float Ks[CHK][64];   // 16,384 B, chunk-swizzled

    const int tid = threadIdx.x;
    const int tx = tid & 15, ty = tid >> 4;
    const int q0 = blockIdx.x * TQ;
    const int bh = blockIdx.y;
    const int b = bh / NHEADS, h = bh - b * NHEADS;
    const size_t qbase = (size_t)b * NSEQ * C3 + h * HD;

    // load Q tile [16][64]: exactly one float4 per thread
    {
        const int qi = q0 + ty;
        float4 v = make_float4(0.f, 0.f, 0.f, 0.f);
        if (qi < NSEQ) v = *(const float4*)(qkv + qbase + (size_t)qi * C3 + tx * 4);
        *(float4*)&Qs[ty][tx * 4] = v;
    }

    const float scale = 0.125f;
    float p[NCH][4];   // all indexing compile-time (loops fully unrolled) -> stays in VGPRs

#pragma unroll
    for (int ch = 0; ch < NCH; ch++) {
        __syncthreads();  // previous K chunk consumed (and Qs visible for ch==0)
        // stage K chunk [64 keys][64 d], swizzled: chunk c4 of row r stored at c4 ^ (r>>2)
#pragma unroll
        for (int l = 0; l < 4; l++) {
            const int fl = tid + l * 256;
            const int row = fl >> 4, c4 = fl & 15;
            const int kk = ch * CHK + row;
            float4 v = make_float4(0.f, 0.f, 0.f, 0.f);
            if (kk < NSEQ)
                v = *(const float4*)(qkv + qbase + DIMC + (size_t)kk * C3 + c4 * 4);
            *(float4*)&Ks[row][(c4 ^ (row >> 2)) * 4] = v;
        }
        __syncthreads();

        float a0 = 0.f, a1 = 0.f, a2 = 0.f, a3 = 0.f;
#pragma unroll
        for (int d4 = 0; d4 < 16; d4++) {
            const float4 q = *(const float4*)&Qs[ty][d4 * 4];
            const int sc = (d4 ^ tx) * 4;   // un-swizzle: rows 4tx..4tx+3 have row>>2 == tx
            const float4 k0 = *(const float4*)&Ks[tx * 4 + 0][sc];
            const float4 k1 = *(const float4*)&Ks[tx * 4 + 1][sc];
            const float4 k2 = *(const float4*)&Ks[tx * 4 + 2][sc];
            const float4 k3 = *(const float4*)&Ks[tx * 4 + 3][sc];
            a0 = fmaf(q.x, k0.x, fmaf(q.y, k0.y, fmaf(q.z, k0.z, fmaf(q.w, k0.w, a0))));
            a1 = fmaf(q.x, k1.x, fmaf(q.y, k1.y, fmaf(q.z, k1.z, fmaf(q.w, k1.w, a1))));
            a2 = fmaf(q.x, k2.x, fmaf(q.y, k2.y, fmaf(q.z, k2.z, fmaf(q.w, k2.w, a2))));
            a3 = fmaf(q.x, k3.x, fmaf(q.y, k3.y, fmaf(q.z, k3.z, fmaf(q.w, k3.w, a3))));
        }
        p[ch][0] = a0 * scale;
        p[ch][1] = a1 * scale;
        p[ch][2] = a2 * scale;
        p[ch][3] = a3 * scale;
    }

    // ---- mask tail keys (ch==9 covers cols 576..639; valid < 596 -> 4tx+j < 20) ----
#pragma unroll
    for (int jj = 0; jj < 4; jj++)
        if (4 * tx + jj >= 20) p[9][jj] = -1e30f;

    // ---- split softmax on registers; 16 lanes per q-row (contiguous in wave) ----
    // CLS segment = cols 0..19 = (ch==0 && tx<5) exactly (float4-aligned boundary).
    float m0 = -1e30f, m1 = -1e30f;
#pragma unroll
    for (int ch = 0; ch < NCH; ch++) {
        const bool cls = (ch == 0 && tx < 5);
#pragma unroll
        for (int jj = 0; jj < 4; jj++) {
            const float v = p[ch][jj];
            if (cls) m0 = fmaxf(m0, v);
            else     m1 = fmaxf(m1, v);
        }
    }
#pragma unroll
    for (int off = 1; off < 16; off <<= 1) {
        m0 = fmaxf(m0, __shfl_xor(m0, off));
        m1 = fmaxf(m1, __shfl_xor(m1, off));
    }

    float s0 = 0.f, s1 = 0.f;
#pragma unroll
    for (int ch = 0; ch < NCH; ch++) {
        const bool cls = (ch == 0 && tx < 5);
        const float m = cls ? m0 : m1;
#pragma unroll
        for (int jj = 0; jj < 4; jj++) {
            const float e = expf(p[ch][jj] - m);   // masked entries -> exp(-inf) = 0
            p[ch][jj] = e;
            if (cls) s0 += e;
            else     s1 += e;
        }
    }
#pragma unroll
    for (int off = 1; off < 16; off <<= 1) {
        s0 += __shfl_xor(s0, off);
        s1 += __shfl_xor(s1, off);
    }
    const float inv0 = 1.f / s0, inv1 = 1.f / s1;

    const int qi = q0 + ty;
    if (qi < NSEQ) {
        const size_t base = ((size_t)bh * NSEQ + qi) * NSEQ;
#pragma unroll
        for (int ch = 0; ch < NCH; ch++) {
            const int col = ch * CHK + tx * 4;
            if (col < NSEQ) {   // ch==9: tx<5 only; tx==4 ends exactly at 595
                const float inv = (ch == 0 && tx < 5) ? inv0 : inv1;
                float4 v;
                v.x = p[ch][0] * inv;
                v.y = p[ch][1] * inv;
                v.z = p[ch][2] * inv;
                v.w = p[ch][3] * inv;
                *(float4*)(wts + base + col) = v;
            }
        }
    }
}

// ============================================================
// Attention pass B: O[596,64] = Wts[596,596] @ V[596,64] per (b,h)
// ============================================================
__global__ __launch_bounds__(256) void attn_av_kernel(const float* __restrict__ qkv,
                                                      const float* __restrict__ wts,
                                                      float* __restrict__ o) {
    constexpr int TQ = 32, CHK = 64, NCH = 10, LDV = 68;
    __shared__ float Wsh[TQ][LDV];
    __shared__ float Vs[CHK][LDV];

    const int tid = threadIdx.x;
    const int tx = tid & 15, ty = tid >> 4;
    const int q0 = blockIdx.x * TQ;
    const int bh = blockIdx.y;
    const int b = bh / NHEADS, h = bh - b * NHEADS;
    const size_t qbase = (size_t)b * NSEQ * C3 + h * HD;

    float acc[2][4];
#pragma unroll
    for (int r = 0; r < 2; r++)
#pragma unroll
        for (int j = 0; j < 4; j++) acc[r][j] = 0.f;

    for (int ch = 0; ch < NCH; ch++) {
        __syncthreads();
        // load weight chunk [32 q][64 k]
#pragma unroll
        for (int l = 0; l < 2; l++) {
            const int fl = tid + l * 256;
            const int row = fl >> 4, c4 = fl & 15;
            const int qi = q0 + row;
            const int kk = ch * CHK + c4 * 4;
            float4 v = make_float4(0.f, 0.f, 0.f, 0.f);
            if (qi < NSEQ && kk < NSEQ)
                v = *(const float4*)(wts + ((size_t)bh * NSEQ + qi) * NSEQ + kk);
            Wsh[row][c4 * 4 + 0] = v.x;
            Wsh[row][c4 * 4 + 1] = v.y;
            Wsh[row][c4 * 4 + 2] = v.z;
            Wsh[row][c4 * 4 + 3] = v.w;
        }
        // load V chunk [64 k][64 d]
#pragma unroll
        for (int l = 0; l < 4; l++) {
            const int fl = tid + l * 256;
            const int row = fl >> 4, c4 = fl & 15;
            const int kk = ch * CHK + row;
            float4 v = make_float4(0.f, 0.f, 0.f, 0.f);
            if (kk < NSEQ)
                v = *(const float4*)(qkv + qbase + 2 * DIMC + (size_t)kk * C3 + c4 * 4);
            Vs[row][c4 * 4 + 0] = v.x;
            Vs[row][c4 * 4 + 1] = v.y;
            Vs[row][c4 * 4 + 2] = v.z;
            Vs[row][c4 * 4 + 3] = v.w;
        }
        __syncthreads();
#pragma unroll
        for (int k4 = 0; k4 < 16; k4++) {
            const float4 wa = *(const float4*)&Wsh[ty * 2][k4 * 4];
            const float4 wb = *(const float4*)&Wsh[ty * 2 + 1][k4 * 4];
            const float4 v0 = *(const float4*)&Vs[k4 * 4 + 0][tx * 4];
            const float4 v1 = *(const float4*)&Vs[k4 * 4 + 1][tx * 4];
            const float4 v2 = *(const float4*)&Vs[k4 * 4 + 2][tx * 4];
            const float4 v3 = *(const float4*)&Vs[k4 * 4 + 3][tx * 4];
            acc[0][0] += wa.x * v0.x + wa.y * v1.x + wa.z * v2.x + wa.w * v3.x;
            acc[0][1] += wa.x * v0.y + wa.y * v1.y + wa.z * v2.y + wa.w * v3.y;
            acc[0][2] += wa.x * v0.z + wa.y * v1.z + wa.z * v2.z + wa.w * v3.z;
            acc[0][3] += wa.x * v0.w + wa.y * v1.w + wa.z * v2.w + wa.w * v3.w;
            acc[1][0] += wb.x * v0.x + wb.y * v1.x + wb.z * v2.x + wb.w * v3.x;
            acc[1][1] += wb.x * v0.y + wb.y * v1.y + wb.z * v2.y + wb.w * v3.y;
            acc[1][2] += wb.x * v0.z + wb.y * v1.z + wb.z * v2.z + wb.w * v3.z;
            acc[1][3] += wb.x * v0.w + wb.y * v1.w + wb.z * v2.w + wb.w * v3.w;
        }
    }

#pragma unroll
    for (int r = 0; r < 2; r++) {
        const int qi = q0 + ty * 2 + r;
        if (qi < NSEQ) {
            float4 v;
            v.x = acc[r][0]; v.y = acc[r][1]; v.z = acc[r][2]; v.w = acc[r][3];
            *(float4*)(o + (size_t)(b * NSEQ + qi) * DIMC + h * HD + tx * 4) = v;
        }
    }
}

// ============================================================
// launcher
// ============================================================
extern "C" void kernel_launch(void* const* d_in, const int* in_sizes, int n_in,
                              void* d_out, int out_size, void* d_ws, size_t ws_size,
                              hipStream_t stream) {
    const float* x      = (const float*)d_in[0];
    const float* qkv_w  = (const float*)d_in[1];
    const float* qkv_b  = (const float*)d_in[2];
    const float* proj_w = (const float*)d_in[3];
    const float* proj_b = (const float*)d_in[4];
    const float* ln1_g  = (const float*)d_in[5];
    const float* ln1_b  = (const float*)d_in[6];
    const float* ln2_g  = (const float*)d_in[7];
    const float* ln2_b  = (const float*)d_in[8];
    const float* fc1_w  = (const float*)d_in[9];
    const float* fc1_b  = (const float*)d_in[10];
    const float* fc2_w  = (const float*)d_in[11];
    const float* fc2_b  = (const float*)d_in[12];

    float* out0 = (float*)d_out;                       // [16,596,768]
    float* wts  = out0 + (size_t)NT * DIMC;            // [16,12,596,596]

    // workspace layout (floats):
    //   bufA: max(qkv 9536x2304, hidden 9536x3072) = 29,294,592
    //   bufB: 9536x768  (xln -> attn_out -> ln2_out)
    //   bufC: 9536x768  (x1 = x + proj)
    float* bufA = (float*)d_ws;
    float* bufB = bufA + (size_t)NT * HID;
    float* bufC = bufB + (size_t)NT * DIMC;

    float* qkv  = bufA;
    float* xln  = bufB;
    float* obuf = bufB;
    float* x1   = bufC;
    float* hbuf = bufB;
    float* hh   = bufA;

    // 1. LN1
    ln_kernel<<<NT, 256, 0, stream>>>(x, ln1_g, ln1_b, xln);
    // 2. QKV GEMM  [9536,2304]
    gemm_kernel<0><<<dim3(C3 / 128, (NT + 127) / 128), 256, 0, stream>>>(
        xln, qkv_w, qkv_b, nullptr, qkv, NT, C3, DIMC);
    // 3. scores + split softmax -> weights output (16 q-rows per block)
    attn_scores_kernel<<<dim3((NSEQ + 15) / 16, NBATCH * NHEADS), 256, 0, stream>>>(qkv, wts);
    // 4. attn @ V -> obuf [9536,768]
    attn_av_kernel<<<dim3((NSEQ + 31) / 32, NBATCH * NHEADS), 256, 0, stream>>>(qkv, wts, obuf);
    // 5. proj GEMM + residual(x) -> x1
    gemm_kernel<1><<<dim3(DIMC / 128, (NT + 127) / 128), 256, 0, stream>>>(
        obuf, proj_w, proj_b, x, x1, NT, DIMC, DIMC);
    // 6. LN2
    ln_kernel<<<NT, 256, 0, stream>>>(x1, ln2_g, ln2_b, hbuf);
    // 7. FC1 GEMM + GELU -> hh [9536,3072]
    gemm_kernel<2><<<dim3(HID / 128, (NT + 127) / 128), 256, 0, stream>>>(
        hbuf, fc1_w, fc1_b, nullptr, hh, NT, HID, DIMC);
    // 8. FC2 GEMM + residual(x1) -> out0
    gemm_kernel<1><<<dim3(DIMC / 128, (NT + 127) / 128), 256, 0, stream>>>(
        hh, fc2_w, fc2_b, x1, out0, NT, DIMC, HID);
}

// Round 2
// 1684.306 us; speedup vs baseline: 1.7709x; 1.7316x over previous
//
#include <hip/hip_runtime.h>
#include <math.h>

// ---- problem constants ----
constexpr int DIMC   = 768;
constexpr int NHEADS = 12;
constexpr int HD     = 64;
constexpr int NCLS   = 20;
constexpr int HID    = 3072;
constexpr int NBATCH = 16;
constexpr int NSEQ   = 596;
constexpr int NT     = NBATCH * NSEQ;   // 9536 tokens
constexpr int C3     = 3 * DIMC;        // 2304
constexpr int MH     = NT / 2;          // 4768 (FC M-split half)
#define LN_EPS 1e-5f

typedef __attribute__((ext_vector_type(8))) short short8;   // 8 bf16 = 4 VGPR
typedef __attribute__((ext_vector_type(4))) float f32x4;

// ---- bf16 helpers (RN) ----
__device__ __forceinline__ unsigned short bf16_rn(float f) {
    unsigned u = __float_as_uint(f);
    u += 0x7fffu + ((u >> 16) & 1u);
    return (unsigned short)(u >> 16);
}
__device__ __forceinline__ float bf16_tof(unsigned short h) {
    return __uint_as_float(((unsigned)h) << 16);
}

__device__ __forceinline__ float gelu_f(float v) {
    return 0.5f * v * (1.0f + erff(v * 0.70710678118654752f));
}

// async global->LDS, 16B per lane, wave-uniform LDS base
typedef __attribute__((address_space(1))) const unsigned int gu32;
typedef __attribute__((address_space(3))) unsigned int lu32;
#define GLOAD16(gp, lp) __builtin_amdgcn_global_load_lds((gu32*)(gp), (lu32*)(lp), 16, 0, 0)

// ============================================================
// split fp32 -> (hi, lo) bf16 arrays. n4 = n/4.
// ============================================================
__global__ __launch_bounds__(256) void split_kernel(const float* __restrict__ in,
                                                    unsigned short* __restrict__ hi,
                                                    unsigned short* __restrict__ lo,
                                                    int n4) {
    int i = blockIdx.x * 256 + threadIdx.x;
    const int stp = gridDim.x * 256;
    for (; i < n4; i += stp) {
        const float4 v = ((const float4*)in)[i];
        ushort4 h, l;
        h.x = bf16_rn(v.x); l.x = bf16_rn(v.x - bf16_tof(h.x));
        h.y = bf16_rn(v.y); l.y = bf16_rn(v.y - bf16_tof(h.y));
        h.z = bf16_rn(v.z); l.z = bf16_rn(v.z - bf16_tof(h.z));
        h.w = bf16_rn(v.w); l.w = bf16_rn(v.w - bf16_tof(h.w));
        ((ushort4*)hi)[i] = h;
        ((ushort4*)lo)[i] = l;
    }
}

// ============================================================
// LayerNorm: one block (256 thr) per row of 768 -> hi/lo bf16 out
// ============================================================
__global__ __launch_bounds__(256) void ln_kernel(const float* __restrict__ x,
                                                 const float* __restrict__ g,
                                                 const float* __restrict__ b,
                                                 unsigned short* __restrict__ yh,
                                                 unsigned short* __restrict__ yl) {
    const int row = blockIdx.x;
    const float* xr = x + (size_t)row * DIMC;
    const int t = threadIdx.x;
    float v0 = xr[t];
    float v1 = xr[t + 256];
    float v2 = xr[t + 512];
    float s  = v0 + v1 + v2;
    float ss = v0 * v0 + v1 * v1 + v2 * v2;
#pragma unroll
    for (int m = 1; m < 64; m <<= 1) {
        s  += __shfl_xor(s, m);
        ss += __shfl_xor(ss, m);
    }
    __shared__ float ls[4], lss[4];
    const int wid = t >> 6;
    if ((t & 63) == 0) { ls[wid] = s; lss[wid] = ss; }
    __syncthreads();
    s  = ls[0] + ls[1] + ls[2] + ls[3];
    ss = lss[0] + lss[1] + lss[2] + lss[3];
    const float mean = s * (1.0f / DIMC);
    const float var  = ss * (1.0f / DIMC) - mean * mean;
    const float rstd = rsqrtf(var + LN_EPS);
    const size_t base = (size_t)row * DIMC;
#pragma unroll
    for (int e = 0; e < 3; e++) {
        const int c = t + e * 256;
        const float v = (e == 0) ? v0 : (e == 1) ? v1 : v2;
        const float y = (v - mean) * rstd * g[c] + b[c];
        const unsigned short h = bf16_rn(y);
        yh[base + c] = h;
        yl[base + c] = bf16_rn(y - bf16_tof(h));
    }
}

// ============================================================
// MFMA GEMM (bf16x3): Out[M,N] = A[M,K] @ W[N,K]^T + bias (+res | gelu->hi/lo)
// A,W given as hi/lo bf16 (row-major, K contiguous). acc fp32 via
// 16x16x32 MFMA: acc += Ah*Wh + Al*Wh + Ah*Wl  (Al*Wl dropped, ~2^-16 rel).
// 128x128 tile, BK=64, 4 waves (2x2), 64x64 per wave.
// Staging: global_load_lds w=16, LDS linear, source pre-swizzled so
// ds_read_b128 fragment reads hit 8 bank-groups x 2 lanes (free).
// Requires N%128==0, K%64==0. M guarded on stores; A tail over-reads
// stay inside workspace (garbage rows never stored; MFMA rows independent).
// EPI: 0 = bias->f32, 1 = bias+res->f32, 2 = bias+GELU->hi/lo bf16
// ============================================================
template <int EPI>
__global__ __launch_bounds__(256) void mgemm_kernel(
    const unsigned short* __restrict__ Ah, const unsigned short* __restrict__ Al,
    const unsigned short* __restrict__ Wh, const unsigned short* __restrict__ Wl,
    const float* __restrict__ bias, const float* __restrict__ res,
    float* __restrict__ Out, unsigned short* __restrict__ OutH,
    unsigned short* __restrict__ OutL, int M, int N, int K)
{
    __shared__ unsigned short sAh[128 * 64], sAl[128 * 64];
    __shared__ unsigned short sWh[128 * 64], sWl[128 * 64];

    const int tid  = threadIdx.x;
    const int lane = tid & 63, wid = tid >> 6;
    const int m0 = blockIdx.y * 128, n0 = blockIdx.x * 128;
    const int wr = wid >> 1, wc = wid & 1;

    // ---- staging addressing (slot s = (wid*4+t)*64 + lane; r=s>>3, c4=s&7) ----
    const int sr = lane >> 3;                 // row-within-8 == r&7
    const int sg = (lane & 7) ^ sr;           // swizzled source chunk
    size_t goffA[4], goffW[4];
    int ldsoff[4];
#pragma unroll
    for (int t = 0; t < 4; t++) {
        const int r = wid * 32 + t * 8 + sr;
        goffA[t] = (size_t)(m0 + r) * K + sg * 8;
        goffW[t] = (size_t)(n0 + r) * K + sg * 8;
        ldsoff[t] = (wid * 4 + t) * 512;      // ushort elements (1024 B / instr)
    }

    // ---- fragment read offsets (k-invariant) ----
    const int fr = lane & 15, fe = lane >> 4;
    int offA[2][4], offW[2][4];
#pragma unroll
    for (int k32 = 0; k32 < 2; k32++)
#pragma unroll
        for (int i = 0; i < 4; i++) {
            const int cs = ((k32 * 4 + fe) ^ (fr & 7)) * 8;
            offA[k32][i] = (wr * 64 + i * 16 + fr) * 64 + cs;
            offW[k32][i] = (wc * 64 + i * 16 + fr) * 64 + cs;
        }

    f32x4 acc[4][4];
#pragma unroll
    for (int i = 0; i < 4; i++)
#pragma unroll
        for (int j = 0; j < 4; j++) acc[i][j] = {0.f, 0.f, 0.f, 0.f};

    // prologue: stage kt=0
#pragma unroll
    for (int t = 0; t < 4; t++) {
        GLOAD16(Ah + goffA[t], &sAh[ldsoff[t]]);
        GLOAD16(Al + goffA[t], &sAl[ldsoff[t]]);
        GLOAD16(Wh + goffW[t], &sWh[ldsoff[t]]);
        GLOAD16(Wl + goffW[t], &sWl[ldsoff[t]]);
    }

    for (int kt = 0; kt < K; kt += 64) {
        __syncthreads();   // drains vmcnt (stage complete) for all waves
#pragma unroll
        for (int k32 = 0; k32 < 2; k32++) {
            short8 a_h[4], a_l[4], w_h[4], w_l[4];
#pragma unroll
            for (int i = 0; i < 4; i++) {
                a_h[i] = *(const short8*)&sAh[offA[k32][i]];
                a_l[i] = *(const short8*)&sAl[offA[k32][i]];
                w_h[i] = *(const short8*)&sWh[offW[k32][i]];
                w_l[i] = *(const short8*)&sWl[offW[k32][i]];
            }
#pragma unroll
            for (int i = 0; i < 4; i++)
#pragma unroll
                for (int j = 0; j < 4; j++) {
                    acc[i][j] = __builtin_amdgcn_mfma_f32_16x16x32_bf16(a_h[i], w_h[j], acc[i][j], 0, 0, 0);
                    acc[i][j] = __builtin_amdgcn_mfma_f32_16x16x32_bf16(a_l[i], w_h[j], acc[i][j], 0, 0, 0);
                    acc[i][j] = __builtin_amdgcn_mfma_f32_16x16x32_bf16(a_h[i], w_l[j], acc[i][j], 0, 0, 0);
                }
        }
        __syncthreads();   // LDS consumed; safe to overwrite
        if (kt + 64 < K) {
            const size_t ka = (size_t)(kt + 64);
#pragma unroll
            for (int t = 0; t < 4; t++) {
                GLOAD16(Ah + goffA[t] + ka, &sAh[ldsoff[t]]);
                GLOAD16(Al + goffA[t] + ka, &sAl[ldsoff[t]]);
                GLOAD16(Wh + goffW[t] + ka, &sWh[ldsoff[t]]);
                GLOAD16(Wl + goffW[t] + ka, &sWl[ldsoff[t]]);
            }
        }
    }

    // ---- epilogue: C/D layout col=lane&15, row=(lane>>4)*4+q ----
#pragma unroll
    for (int j = 0; j < 4; j++) {
        const int col = n0 + wc * 64 + j * 16 + fr;
        const float bj = bias[col];
#pragma unroll
        for (int i = 0; i < 4; i++) {
            const int row0 = m0 + wr * 64 + i * 16 + fe * 4;
#pragma unroll
            for (int q = 0; q < 4; q++) {
                const int gm = row0 + q;
                if (gm < M) {
                    const size_t idx = (size_t)gm * N + col;
                    float v = acc[i][j][q] + bj;
                    if (EPI == 1) v += res[idx];
                    if (EPI == 2) {
                        v = gelu_f(v);
                        const unsigned short hh = bf16_rn(v);
                        OutH[idx] = hh;
                        OutL[idx] = bf16_rn(v - bf16_tof(hh));
                    } else {
                        Out[idx] = v;
                    }
                }
            }
        }
    }
}

// ============================================================
// Attention pass A: scores in registers + swizzled K tile (round-1 version)
// ============================================================
__global__ __launch_bounds__(256) void attn_scores_kernel(const float* __restrict__ qkv,
                                                          float* __restrict__ wts) {
    constexpr int TQ = 16, CHK = 64, NCH = 10;
    __shared__ float Qs[TQ][68];
    __shared__ float Ks[CHK][64];

    const int tid = threadIdx.x;
    const int tx = tid & 15, ty = tid >> 4;
    const int q0 = blockIdx.x * TQ;
    const int bh = blockIdx.y;
    const int b = bh / NHEADS, h = bh - b * NHEADS;
    const size_t qbase = (size_t)b * NSEQ * C3 + h * HD;

    {
        const int qi = q0 + ty;
        float4 v = make_float4(0.f, 0.f, 0.f, 0.f);
        if (qi < NSEQ) v = *(const float4*)(qkv + qbase + (size_t)qi * C3 + tx * 4);
        *(float4*)&Qs[ty][tx * 4] = v;
    }

    const float scale = 0.125f;
    float p[NCH][4];

#pragma unroll
    for (int ch = 0; ch < NCH; ch++) {
        __syncthreads();
#pragma unroll
        for (int l = 0; l < 4; l++) {
            const int fl = tid + l * 256;
            const int row = fl >> 4, c4 = fl & 15;
            const int kk = ch * CHK + row;
            float4 v = make_float4(0.f, 0.f, 0.f, 0.f);
            if (kk < NSEQ)
                v = *(const float4*)(qkv + qbase + DIMC + (size_t)kk * C3 + c4 * 4);
            *(float4*)&Ks[row][(c4 ^ (row >> 2)) * 4] = v;
        }
        __syncthreads();

        float a0 = 0.f, a1 = 0.f, a2 = 0.f, a3 = 0.f;
#pragma unroll
        for (int d4 = 0; d4 < 16; d4++) {
            const float4 q = *(const float4*)&Qs[ty][d4 * 4];
            const int sc = (d4 ^ tx) * 4;
            const float4 k0 = *(const float4*)&Ks[tx * 4 + 0][sc];
            const float4 k1 = *(const float4*)&Ks[tx * 4 + 1][sc];
            const float4 k2 = *(const float4*)&Ks[tx * 4 + 2][sc];
            const float4 k3 = *(const float4*)&Ks[tx * 4 + 3][sc];
            a0 = fmaf(q.x, k0.x, fmaf(q.y, k0.y, fmaf(q.z, k0.z, fmaf(q.w, k0.w, a0))));
            a1 = fmaf(q.x, k1.x, fmaf(q.y, k1.y, fmaf(q.z, k1.z, fmaf(q.w, k1.w, a1))));
            a2 = fmaf(q.x, k2.x, fmaf(q.y, k2.y, fmaf(q.z, k2.z, fmaf(q.w, k2.w, a2))));
            a3 = fmaf(q.x, k3.x, fmaf(q.y, k3.y, fmaf(q.z, k3.z, fmaf(q.w, k3.w, a3))));
        }
        p[ch][0] = a0 * scale;
        p[ch][1] = a1 * scale;
        p[ch][2] = a2 * scale;
        p[ch][3] = a3 * scale;
    }

#pragma unroll
    for (int jj = 0; jj < 4; jj++)
        if (4 * tx + jj >= 20) p[9][jj] = -1e30f;

    float m0 = -1e30f, m1 = -1e30f;
#pragma unroll
    for (int ch = 0; ch < NCH; ch++) {
        const bool cls = (ch == 0 && tx < 5);
#pragma unroll
        for (int jj = 0; jj < 4; jj++) {
            const float v = p[ch][jj];
            if (cls) m0 = fmaxf(m0, v);
            else     m1 = fmaxf(m1, v);
        }
    }
#pragma unroll
    for (int off = 1; off < 16; off <<= 1) {
        m0 = fmaxf(m0, __shfl_xor(m0, off));
        m1 = fmaxf(m1, __shfl_xor(m1, off));
    }

    float s0 = 0.f, s1 = 0.f;
#pragma unroll
    for (int ch = 0; ch < NCH; ch++) {
        const bool cls = (ch == 0 && tx < 5);
        const float m = cls ? m0 : m1;
#pragma unroll
        for (int jj = 0; jj < 4; jj++) {
            const float e = expf(p[ch][jj] - m);
            p[ch][jj] = e;
            if (cls) s0 += e;
            else     s1 += e;
        }
    }
#pragma unroll
    for (int off = 1; off < 16; off <<= 1) {
        s0 += __shfl_xor(s0, off);
        s1 += __shfl_xor(s1, off);
    }
    const float inv0 = 1.f / s0, inv1 = 1.f / s1;

    const int qi = q0 + ty;
    if (qi < NSEQ) {
        const size_t base = ((size_t)bh * NSEQ + qi) * NSEQ;
#pragma unroll
        for (int ch = 0; ch < NCH; ch++) {
            const int col = ch * CHK + tx * 4;
            if (col < NSEQ) {
                const float inv = (ch == 0 && tx < 5) ? inv0 : inv1;
                float4 v;
                v.x = p[ch][0] * inv;
                v.y = p[ch][1] * inv;
                v.z = p[ch][2] * inv;
                v.w = p[ch][3] * inv;
                *(float4*)(wts + base + col) = v;
            }
        }
    }
}

// ============================================================
// Attention pass B: O = Wts @ V per (b,h) -> hi/lo bf16 output
// ============================================================
__global__ __launch_bounds__(256) void attn_av_kernel(const float* __restrict__ qkv,
                                                      const float* __restrict__ wts,
                                                      unsigned short* __restrict__ ohi,
                                                      unsigned short* __restrict__ olo) {
    constexpr int TQ = 32, CHK = 64, NCH = 10, LDV = 68;
    __shared__ float Wsh[TQ][LDV];
    __shared__ float Vs[CHK][LDV];

    const int tid = threadIdx.x;
    const int tx = tid & 15, ty = tid >> 4;
    const int q0 = blockIdx.x * TQ;
    const int bh = blockIdx.y;
    const int b = bh / NHEADS, h = bh - b * NHEADS;
    const size_t qbase = (size_t)b * NSEQ * C3 + h * HD;

    float acc[2][4];
#pragma unroll
    for (int r = 0; r < 2; r++)
#pragma unroll
        for (int j = 0; j < 4; j++) acc[r][j] = 0.f;

    for (int ch = 0; ch < NCH; ch++) {
        __syncthreads();
#pragma unroll
        for (int l = 0; l < 2; l++) {
            const int fl = tid + l * 256;
            const int row = fl >> 4, c4 = fl & 15;
            const int qi = q0 + row;
            const int kk = ch * CHK + c4 * 4;
            float4 v = make_float4(0.f, 0.f, 0.f, 0.f);
            if (qi < NSEQ && kk < NSEQ)
                v = *(const float4*)(wts + ((size_t)bh * NSEQ + qi) * NSEQ + kk);
            Wsh[row][c4 * 4 + 0] = v.x;
            Wsh[row][c4 * 4 + 1] = v.y;
            Wsh[row][c4 * 4 + 2] = v.z;
            Wsh[row][c4 * 4 + 3] = v.w;
        }
#pragma unroll
        for (int l = 0; l < 4; l++) {
            const int fl = tid + l * 256;
            const int row = fl >> 4, c4 = fl & 15;
            const int kk = ch * CHK + row;
            float4 v = make_float4(0.f, 0.f, 0.f, 0.f);
            if (kk < NSEQ)
                v = *(const float4*)(qkv + qbase + 2 * DIMC + (size_t)kk * C3 + c4 * 4);
            Vs[row][c4 * 4 + 0] = v.x;
            Vs[row][c4 * 4 + 1] = v.y;
            Vs[row][c4 * 4 + 2] = v.z;
            Vs[row][c4 * 4 + 3] = v.w;
        }
        __syncthreads();
#pragma unroll
        for (int k4 = 0; k4 < 16; k4++) {
            const float4 wa = *(const float4*)&Wsh[ty * 2][k4 * 4];
            const float4 wb = *(const float4*)&Wsh[ty * 2 + 1][k4 * 4];
            const float4 v0 = *(const float4*)&Vs[k4 * 4 + 0][tx * 4];
            const float4 v1 = *(const float4*)&Vs[k4 * 4 + 1][tx * 4];
            const float4 v2 = *(const float4*)&Vs[k4 * 4 + 2][tx * 4];
            const float4 v3 = *(const float4*)&Vs[k4 * 4 + 3][tx * 4];
            acc[0][0] += wa.x * v0.x + wa.y * v1.x + wa.z * v2.x + wa.w * v3.x;
            acc[0][1] += wa.x * v0.y + wa.y * v1.y + wa.z * v2.y + wa.w * v3.y;
            acc[0][2] += wa.x * v0.z + wa.y * v1.z + wa.z * v2.z + wa.w * v3.z;
            acc[0][3] += wa.x * v0.w + wa.y * v1.w + wa.z * v2.w + wa.w * v3.w;
            acc[1][0] += wb.x * v0.x + wb.y * v1.x + wb.z * v2.x + wb.w * v3.x;
            acc[1][1] += wb.x * v0.y + wb.y * v1.y + wb.z * v2.y + wb.w * v3.y;
            acc[1][2] += wb.x * v0.z + wb.y * v1.z + wb.z * v2.z + wb.w * v3.z;
            acc[1][3] += wb.x * v0.w + wb.y * v1.w + wb.z * v2.w + wb.w * v3.w;
        }
    }

#pragma unroll
    for (int r = 0; r < 2; r++) {
        const int qi = q0 + ty * 2 + r;
        if (qi < NSEQ) {
            const size_t idx = (size_t)(b * NSEQ + qi) * DIMC + h * HD + tx * 4;
            ushort4 hv, lv;
            hv.x = bf16_rn(acc[r][0]); lv.x = bf16_rn(acc[r][0] - bf16_tof(hv.x));
            hv.y = bf16_rn(acc[r][1]); lv.y = bf16_rn(acc[r][1] - bf16_tof(hv.y));
            hv.z = bf16_rn(acc[r][2]); lv.z = bf16_rn(acc[r][2] - bf16_tof(hv.z));
            hv.w = bf16_rn(acc[r][3]); lv.w = bf16_rn(acc[r][3] - bf16_tof(hv.w));
            *(ushort4*)(ohi + idx) = hv;
            *(ushort4*)(olo + idx) = lv;
        }
    }
}

// ============================================================
// launcher
// ============================================================
extern "C" void kernel_launch(void* const* d_in, const int* in_sizes, int n_in,
                              void* d_out, int out_size, void* d_ws, size_t ws_size,
                              hipStream_t stream) {
    const float* x      = (const float*)d_in[0];
    const float* qkv_w  = (const float*)d_in[1];
    const float* qkv_b  = (const float*)d_in[2];
    const float* proj_w = (const float*)d_in[3];
    const float* proj_b = (const float*)d_in[4];
    const float* ln1_g  = (const float*)d_in[5];
    const float* ln1_b  = (const float*)d_in[6];
    const float* ln2_g  = (const float*)d_in[7];
    const float* ln2_b  = (const float*)d_in[8];
    const float* fc1_w  = (const float*)d_in[9];
    const float* fc1_b  = (const float*)d_in[10];
    const float* fc2_w  = (const float*)d_in[11];
    const float* fc2_b  = (const float*)d_in[12];

    float* out0 = (float*)d_out;                       // [16,596,768]
    float* wts  = out0 + (size_t)NT * DIMC;            // [16,12,596,596]

    // ---- workspace layout (174.8 MB total; old layout was 175.8 MB) ----
    // Q region (87.9 MB): qkv fp32 [NT,2304]  ->  later hh hi/lo [MH,3072] bf16 x2 (58.7 MB)
    // S region (29.3 MB): hi/lo [NT,768] bf16 (xln -> attn_out -> ln2_out)
    // x1       (29.3 MB): fp32 [NT,768]
    // W region (28.3 MB): weight hi/lo bf16
    char* ws = (char*)d_ws;
    float* qkv = (float*)ws;
    unsigned short* hh_h = (unsigned short*)ws;                 // overlays qkv (dead by then)
    unsigned short* hh_l = hh_h + (size_t)MH * HID;
    char* sReg = ws + (size_t)NT * C3 * 4;
    unsigned short* s_h = (unsigned short*)sReg;
    unsigned short* s_l = s_h + (size_t)NT * DIMC;
    float* x1 = (float*)(sReg + (size_t)NT * DIMC * 4);         // after s_h+s_l
    char* wReg = (char*)x1 + (size_t)NT * DIMC * 4;
    unsigned short* qw_h = (unsigned short*)wReg;
    unsigned short* qw_l = qw_h + (size_t)C3 * DIMC;
    unsigned short* pw_h = qw_l + (size_t)C3 * DIMC;
    unsigned short* pw_l = pw_h + (size_t)DIMC * DIMC;
    unsigned short* f1_h = pw_l + (size_t)DIMC * DIMC;
    unsigned short* f1_l = f1_h + (size_t)HID * DIMC;
    unsigned short* f2_h = f1_l + (size_t)HID * DIMC;
    unsigned short* f2_l = f2_h + (size_t)DIMC * HID;

    // 1. LN1 -> hi/lo bf16
    ln_kernel<<<NT, 256, 0, stream>>>(x, ln1_g, ln1_b, s_h, s_l);
    // 1b. weight splits
    split_kernel<<<1024, 256, 0, stream>>>(qkv_w, qw_h, qw_l, C3 * DIMC / 4);
    split_kernel<<<576, 256, 0, stream>>>(proj_w, pw_h, pw_l, DIMC * DIMC / 4);
    split_kernel<<<1024, 256, 0, stream>>>(fc1_w, f1_h, f1_l, HID * DIMC / 4);
    split_kernel<<<1024, 256, 0, stream>>>(fc2_w, f2_h, f2_l, DIMC * HID / 4);
    // 2. QKV GEMM -> qkv fp32
    mgemm_kernel<0><<<dim3(C3 / 128, (NT + 127) / 128), 256, 0, stream>>>(
        s_h, s_l, qw_h, qw_l, qkv_b, nullptr, qkv, nullptr, nullptr, NT, C3, DIMC);
    // 3. scores + split softmax -> weights output
    attn_scores_kernel<<<dim3((NSEQ + 15) / 16, NBATCH * NHEADS), 256, 0, stream>>>(qkv, wts);
    // 4. attn @ V -> hi/lo bf16 in S region (xln dead)
    attn_av_kernel<<<dim3((NSEQ + 31) / 32, NBATCH * NHEADS), 256, 0, stream>>>(qkv, wts, s_h, s_l);
    // 5. proj GEMM + residual(x) -> x1 fp32
    mgemm_kernel<1><<<dim3(DIMC / 128, (NT + 127) / 128), 256, 0, stream>>>(
        s_h, s_l, pw_h, pw_l, proj_b, x, x1, nullptr, nullptr, NT, DIMC, DIMC);
    // 6. LN2 -> hi/lo bf16 in S region (attn_out dead)
    ln_kernel<<<NT, 256, 0, stream>>>(x1, ln2_g, ln2_b, s_h, s_l);
    // 7/8. FC1 (GELU -> hh hi/lo over dead qkv) + FC2 (+residual x1) in M-halves
    for (int hf = 0; hf < 2; hf++) {
        const size_t r0 = (size_t)hf * MH;
        mgemm_kernel<2><<<dim3(HID / 128, (MH + 127) / 128), 256, 0, stream>>>(
            s_h + r0 * DIMC, s_l + r0 * DIMC, f1_h, f1_l, fc1_b, nullptr,
            nullptr, hh_h, hh_l, MH, HID, DIMC);
        mgemm_kernel<1><<<dim3(DIMC / 128, (MH + 127) / 128), 256, 0, stream>>>(
            hh_h, hh_l, f2_h, f2_l, fc2_b, x1 + r0 * DIMC,
            out0 + r0 * DIMC, nullptr, nullptr, MH, DIMC, HID);
    }
}

// Round 4
// 1244.835 us; speedup vs baseline: 2.3961x; 1.3530x over previous
//
#include <hip/hip_runtime.h>
#include <math.h>

// ---- problem constants ----
constexpr int DIMC   = 768;
constexpr int NHEADS = 12;
constexpr int HD     = 64;
constexpr int NCLS   = 20;
constexpr int HID    = 3072;
constexpr int NBATCH = 16;
constexpr int NSEQ   = 596;
constexpr int NT     = NBATCH * NSEQ;   // 9536 tokens
constexpr int C3     = 3 * DIMC;        // 2304
constexpr int MH     = NT / 2;          // 4768 (FC M-split half)
#define LN_EPS 1e-5f

typedef __attribute__((ext_vector_type(8))) short short8;   // 8 bf16 = 4 VGPR
typedef __attribute__((ext_vector_type(4))) float f32x4;

// ---- bf16 helpers (RN) ----
__device__ __forceinline__ unsigned short bf16_rn(float f) {
    unsigned u = __float_as_uint(f);
    u += 0x7fffu + ((u >> 16) & 1u);
    return (unsigned short)(u >> 16);
}
__device__ __forceinline__ float bf16_tof(unsigned short h) {
    return __uint_as_float(((unsigned)h) << 16);
}

__device__ __forceinline__ float gelu_f(float v) {
    return 0.5f * v * (1.0f + erff(v * 0.70710678118654752f));
}

// async global->LDS, 16B per lane, wave-uniform LDS base
typedef __attribute__((address_space(1))) const unsigned int gu32;
typedef __attribute__((address_space(3))) unsigned int lu32;
#define GLOAD16(gp, lp) __builtin_amdgcn_global_load_lds((gu32*)(gp), (lu32*)(lp), 16, 0, 0)

// ============================================================
// split fp32 -> (hi, lo) bf16 arrays. n4 = n/4.
// ============================================================
__global__ __launch_bounds__(256) void split_kernel(const float* __restrict__ in,
                                                    unsigned short* __restrict__ hi,
                                                    unsigned short* __restrict__ lo,
                                                    int n4) {
    int i = blockIdx.x * 256 + threadIdx.x;
    const int stp = gridDim.x * 256;
    for (; i < n4; i += stp) {
        const float4 v = ((const float4*)in)[i];
        ushort4 h, l;
        h.x = bf16_rn(v.x); l.x = bf16_rn(v.x - bf16_tof(h.x));
        h.y = bf16_rn(v.y); l.y = bf16_rn(v.y - bf16_tof(h.y));
        h.z = bf16_rn(v.z); l.z = bf16_rn(v.z - bf16_tof(h.z));
        h.w = bf16_rn(v.w); l.w = bf16_rn(v.w - bf16_tof(h.w));
        ((ushort4*)hi)[i] = h;
        ((ushort4*)lo)[i] = l;
    }
}

// ============================================================
// LayerNorm: one block (256 thr) per row of 768 -> hi/lo bf16 out
// ============================================================
__global__ __launch_bounds__(256) void ln_kernel(const float* __restrict__ x,
                                                 const float* __restrict__ g,
                                                 const float* __restrict__ b,
                                                 unsigned short* __restrict__ yh,
                                                 unsigned short* __restrict__ yl) {
    const int row = blockIdx.x;
    const float* xr = x + (size_t)row * DIMC;
    const int t = threadIdx.x;
    float v0 = xr[t];
    float v1 = xr[t + 256];
    float v2 = xr[t + 512];
    float s  = v0 + v1 + v2;
    float ss = v0 * v0 + v1 * v1 + v2 * v2;
#pragma unroll
    for (int m = 1; m < 64; m <<= 1) {
        s  += __shfl_xor(s, m);
        ss += __shfl_xor(ss, m);
    }
    __shared__ float ls[4], lss[4];
    const int wid = t >> 6;
    if ((t & 63) == 0) { ls[wid] = s; lss[wid] = ss; }
    __syncthreads();
    s  = ls[0] + ls[1] + ls[2] + ls[3];
    ss = lss[0] + lss[1] + lss[2] + lss[3];
    const float mean = s * (1.0f / DIMC);
    const float var  = ss * (1.0f / DIMC) - mean * mean;
    const float rstd = rsqrtf(var + LN_EPS);
    const size_t base = (size_t)row * DIMC;
#pragma unroll
    for (int e = 0; e < 3; e++) {
        const int c = t + e * 256;
        const float v = (e == 0) ? v0 : (e == 1) ? v1 : v2;
        const float y = (v - mean) * rstd * g[c] + b[c];
        const unsigned short h = bf16_rn(y);
        yh[base + c] = h;
        yl[base + c] = bf16_rn(y - bf16_tof(h));
    }
}

// ============================================================
// MFMA GEMM (bf16x3): Out[M,N] = A[M,K] @ W[N,K]^T + bias (+res | gelu)
// EPI: 0 bias->f32, 1 bias+res->f32, 2 bias+GELU->hi/lo, 3 bias->hi/lo
// ============================================================
template <int EPI>
__global__ __launch_bounds__(256) void mgemm_kernel(
    const unsigned short* __restrict__ Ah, const unsigned short* __restrict__ Al,
    const unsigned short* __restrict__ Wh, const unsigned short* __restrict__ Wl,
    const float* __restrict__ bias, const float* __restrict__ res,
    float* __restrict__ Out, unsigned short* __restrict__ OutH,
    unsigned short* __restrict__ OutL, int M, int N, int K)
{
    __shared__ unsigned short sAh[128 * 64], sAl[128 * 64];
    __shared__ unsigned short sWh[128 * 64], sWl[128 * 64];

    const int tid  = threadIdx.x;
    const int lane = tid & 63, wid = tid >> 6;
    const int m0 = blockIdx.y * 128, n0 = blockIdx.x * 128;
    const int wr = wid >> 1, wc = wid & 1;

    const int sr = lane >> 3;
    const int sg = (lane & 7) ^ sr;
    size_t goffA[4], goffW[4];
    int ldsoff[4];
#pragma unroll
    for (int t = 0; t < 4; t++) {
        const int r = wid * 32 + t * 8 + sr;
        goffA[t] = (size_t)(m0 + r) * K + sg * 8;
        goffW[t] = (size_t)(n0 + r) * K + sg * 8;
        ldsoff[t] = (wid * 4 + t) * 512;
    }

    const int fr = lane & 15, fe = lane >> 4;
    int offA[2][4], offW[2][4];
#pragma unroll
    for (int k32 = 0; k32 < 2; k32++)
#pragma unroll
        for (int i = 0; i < 4; i++) {
            const int cs = ((k32 * 4 + fe) ^ (fr & 7)) * 8;
            offA[k32][i] = (wr * 64 + i * 16 + fr) * 64 + cs;
            offW[k32][i] = (wc * 64 + i * 16 + fr) * 64 + cs;
        }

    f32x4 acc[4][4];
#pragma unroll
    for (int i = 0; i < 4; i++)
#pragma unroll
        for (int j = 0; j < 4; j++) acc[i][j] = {0.f, 0.f, 0.f, 0.f};

#pragma unroll
    for (int t = 0; t < 4; t++) {
        GLOAD16(Ah + goffA[t], &sAh[ldsoff[t]]);
        GLOAD16(Al + goffA[t], &sAl[ldsoff[t]]);
        GLOAD16(Wh + goffW[t], &sWh[ldsoff[t]]);
        GLOAD16(Wl + goffW[t], &sWl[ldsoff[t]]);
    }

    for (int kt = 0; kt < K; kt += 64) {
        __syncthreads();
#pragma unroll
        for (int k32 = 0; k32 < 2; k32++) {
            short8 a_h[4], a_l[4], w_h[4], w_l[4];
#pragma unroll
            for (int i = 0; i < 4; i++) {
                a_h[i] = *(const short8*)&sAh[offA[k32][i]];
                a_l[i] = *(const short8*)&sAl[offA[k32][i]];
                w_h[i] = *(const short8*)&sWh[offW[k32][i]];
                w_l[i] = *(const short8*)&sWl[offW[k32][i]];
            }
#pragma unroll
            for (int i = 0; i < 4; i++)
#pragma unroll
                for (int j = 0; j < 4; j++) {
                    acc[i][j] = __builtin_amdgcn_mfma_f32_16x16x32_bf16(a_h[i], w_h[j], acc[i][j], 0, 0, 0);
                    acc[i][j] = __builtin_amdgcn_mfma_f32_16x16x32_bf16(a_l[i], w_h[j], acc[i][j], 0, 0, 0);
                    acc[i][j] = __builtin_amdgcn_mfma_f32_16x16x32_bf16(a_h[i], w_l[j], acc[i][j], 0, 0, 0);
                }
        }
        __syncthreads();
        if (kt + 64 < K) {
            const size_t ka = (size_t)(kt + 64);
#pragma unroll
            for (int t = 0; t < 4; t++) {
                GLOAD16(Ah + goffA[t] + ka, &sAh[ldsoff[t]]);
                GLOAD16(Al + goffA[t] + ka, &sAl[ldsoff[t]]);
                GLOAD16(Wh + goffW[t] + ka, &sWh[ldsoff[t]]);
                GLOAD16(Wl + goffW[t] + ka, &sWl[ldsoff[t]]);
            }
        }
    }

#pragma unroll
    for (int j = 0; j < 4; j++) {
        const int col = n0 + wc * 64 + j * 16 + fr;
        const float bj = bias[col];
#pragma unroll
        for (int i = 0; i < 4; i++) {
            const int row0 = m0 + wr * 64 + i * 16 + fe * 4;
#pragma unroll
            for (int q = 0; q < 4; q++) {
                const int gm = row0 + q;
                if (gm < M) {
                    const size_t idx = (size_t)gm * N + col;
                    float v = acc[i][j][q] + bj;
                    if (EPI == 1) v += res[idx];
                    if (EPI == 2) {
                        v = gelu_f(v);
                        const unsigned short hh = bf16_rn(v);
                        OutH[idx] = hh;
                        OutL[idx] = bf16_rn(v - bf16_tof(hh));
                    } else if (EPI == 3) {
                        const unsigned short hh = bf16_rn(v);
                        OutH[idx] = hh;
                        OutL[idx] = bf16_rn(v - bf16_tof(hh));
                    } else {
                        Out[idx] = v;
                    }
                }
            }
        }
    }
}

// ============================================================
// Fused MFMA attention (bf16x3): per block (bh, 64 q-rows), 4 waves x 16q.
// qkv given as hi/lo bf16 [NT][2304] (Q@0, K@768, V@1536 per row, +h*64).
// Pass 1: stream K chunks (gload_lds w=16, src pre-swizzled chunk^row),
//   scores = mfma(Q,K)x3, two-segment (CLS<20 | patch) online max+sum.
// Pass 2: restage K (L2-hot), recompute scores, w=exp(s-m)*inv,
//   write wts (fp32 output), transpose P via per-wave LDS, stage V^T in
//   LDS (b32-packed, swizzle (key>>3)^(d&7)^(d>>3): read-conflict-free),
//   O += mfma(P,V)x3 -> hi/lo bf16 out.
// Staging key index clamped to NSEQ-1 (rows masked in compute) so all
// global reads stay inside the qkv arrays.
// ============================================================
__global__ __launch_bounds__(256) void fattn_kernel(
    const unsigned short* __restrict__ gqh, const unsigned short* __restrict__ gql,
    float* __restrict__ wts,
    unsigned short* __restrict__ oh, unsigned short* __restrict__ ol)
{
    __shared__ unsigned short Kh[4096], Kl[4096];   // [64 key][64 d], chunk^=(row&7)
    __shared__ unsigned short Vh[4096], Vl[4096];   // [64 d][64 key], chunk^=(d&7)^(d>>3)
    __shared__ float Plds[4][16 * 68];              // per-wave P transpose

    const int tid = threadIdx.x;
    const int lane = tid & 63, w = tid >> 6;
    const int fr = lane & 15, fe = lane >> 4;
    const int bh = blockIdx.x;
    const int b = bh / NHEADS, h = bh - b * NHEADS;
    const int q0 = blockIdx.y * 64 + w * 16;
    const size_t tokbase = (size_t)b * NSEQ;
    const size_t hoff = (size_t)h * HD;
    const size_t wbase = (size_t)bh * NSEQ * NSEQ;

    // ---- Q A-frags (row=lane&15, k=fe*8+j), guarded ----
    short8 qfh[2], qfl[2];
    {
        const short8 z8 = {0, 0, 0, 0, 0, 0, 0, 0};
        qfh[0] = z8; qfh[1] = z8; qfl[0] = z8; qfl[1] = z8;
        const int qi = q0 + fr;
        if (qi < NSEQ) {
            const size_t base = (tokbase + qi) * C3 + hoff + fe * 8;
            qfh[0] = *(const short8*)(gqh + base);
            qfh[1] = *(const short8*)(gqh + base + 32);
            qfl[0] = *(const short8*)(gql + base);
            qfl[1] = *(const short8*)(gql + base + 32);
        }
    }

    const int srow = lane >> 3;             // staging row-in-8
    const int sc8 = (lane & 7) ^ srow;      // swizzled source d-chunk

    float mc[4], mp[4], lc[4], lp[4];
#pragma unroll
    for (int r = 0; r < 4; r++) { mc[r] = -3e38f; mp[r] = -3e38f; lc[r] = 0.f; lp[r] = 0.f; }

    // ================= pass 1: online max+sum =================
    for (int ch = 0; ch < 10; ch++) {
        __syncthreads();
#pragma unroll
        for (int i = 0; i < 2; i++) {
            const int s = w + i * 4;
            const int key = min(ch * 64 + s * 8 + srow, NSEQ - 1);   // clamp: masked rows re-read key 595
            const size_t src = (tokbase + key) * C3 + DIMC + hoff + sc8 * 8;
            GLOAD16(gqh + src, &Kh[s * 512]);
            GLOAD16(gql + src, &Kl[s * 512]);
        }
        __syncthreads();

        f32x4 sc_[4];
#pragma unroll
        for (int t = 0; t < 4; t++) sc_[t] = {0.f, 0.f, 0.f, 0.f};
#pragma unroll
        for (int k32 = 0; k32 < 2; k32++)
#pragma unroll
            for (int t = 0; t < 4; t++) {
                const int pos = (t * 16 + fr) * 64 + ((k32 * 4 + fe) ^ (fr & 7)) * 8;
                const short8 kbh = *(const short8*)&Kh[pos];
                const short8 kbl = *(const short8*)&Kl[pos];
                sc_[t] = __builtin_amdgcn_mfma_f32_16x16x32_bf16(qfh[k32], kbh, sc_[t], 0, 0, 0);
                sc_[t] = __builtin_amdgcn_mfma_f32_16x16x32_bf16(qfl[k32], kbh, sc_[t], 0, 0, 0);
                sc_[t] = __builtin_amdgcn_mfma_f32_16x16x32_bf16(qfh[k32], kbl, sc_[t], 0, 0, 0);
            }

        float sv[4][4];
#pragma unroll
        for (int t = 0; t < 4; t++)
#pragma unroll
            for (int r = 0; r < 4; r++) {
                float v = sc_[t][r] * 0.125f;
                if (ch * 64 + t * 16 + fr >= NSEQ) v = -3e38f;
                sv[t][r] = v;
            }

        if (ch == 0) {
#pragma unroll
            for (int r = 0; r < 4; r++) {
                float xc = -3e38f, xp = -3e38f;
#pragma unroll
                for (int t = 0; t < 4; t++) {
                    const bool cls = (t == 0) || (t == 1 && fr < 4);
                    if (cls) xc = fmaxf(xc, sv[t][r]); else xp = fmaxf(xp, sv[t][r]);
                }
#pragma unroll
                for (int o = 1; o < 16; o <<= 1) {
                    xc = fmaxf(xc, __shfl_xor(xc, o));
                    xp = fmaxf(xp, __shfl_xor(xp, o));
                }
                const float mcn = fmaxf(mc[r], xc), mpn = fmaxf(mp[r], xp);
                float ec = 0.f, ep = 0.f;
#pragma unroll
                for (int t = 0; t < 4; t++) {
                    const bool cls = (t == 0) || (t == 1 && fr < 4);
                    const float e = expf(sv[t][r] - (cls ? mcn : mpn));
                    if (cls) ec += e; else ep += e;
                }
#pragma unroll
                for (int o = 1; o < 16; o <<= 1) {
                    ec += __shfl_xor(ec, o);
                    ep += __shfl_xor(ep, o);
                }
                lc[r] = lc[r] * expf(mc[r] - mcn) + ec;
                lp[r] = lp[r] * expf(mp[r] - mpn) + ep;
                mc[r] = mcn; mp[r] = mpn;
            }
        } else {
#pragma unroll
            for (int r = 0; r < 4; r++) {
                float xp = fmaxf(fmaxf(sv[0][r], sv[1][r]), fmaxf(sv[2][r], sv[3][r]));
#pragma unroll
                for (int o = 1; o < 16; o <<= 1) xp = fmaxf(xp, __shfl_xor(xp, o));
                const float mpn = fmaxf(mp[r], xp);
                float ep = 0.f;
#pragma unroll
                for (int t = 0; t < 4; t++) ep += expf(sv[t][r] - mpn);
#pragma unroll
                for (int o = 1; o < 16; o <<= 1) ep += __shfl_xor(ep, o);
                lp[r] = lp[r] * expf(mp[r] - mpn) + ep;
                mp[r] = mpn;
            }
        }
    }

    float ic[4], ip[4];
#pragma unroll
    for (int r = 0; r < 4; r++) { ic[r] = 1.f / lc[r]; ip[r] = 1.f / lp[r]; }

    // ================= pass 2: wts + PV =================
    f32x4 oacc[4];
#pragma unroll
    for (int dt = 0; dt < 4; dt++) oacc[dt] = {0.f, 0.f, 0.f, 0.f};

    const int dgq = tid & 7;     // V-stage d-group
    const int kp  = tid >> 3;    // V-stage key-pair (0..31)

    for (int ch = 0; ch < 10; ch++) {
        __syncthreads();
        // restage K
#pragma unroll
        for (int i = 0; i < 2; i++) {
            const int s = w + i * 4;
            const int key = min(ch * 64 + s * 8 + srow, NSEQ - 1);
            const size_t src = (tokbase + key) * C3 + DIMC + hoff + sc8 * 8;
            GLOAD16(gqh + src, &Kh[s * 512]);
            GLOAD16(gql + src, &Kl[s * 512]);
        }
        // stage V^T (coalesced reg load, packed b32 transposed LDS write)
        {
            const short8 z8 = {0, 0, 0, 0, 0, 0, 0, 0};
            short8 vah = z8, vAl = z8, vbh = z8, vbl = z8;
            const int keyA = ch * 64 + kp * 2;
            if (keyA < NSEQ) {
                const size_t oA = (tokbase + keyA) * C3 + 2 * DIMC + hoff + dgq * 8;
                vah = *(const short8*)(gqh + oA);
                vAl = *(const short8*)(gql + oA);
            }
            if (keyA + 1 < NSEQ) {
                const size_t oB = (tokbase + keyA + 1) * C3 + 2 * DIMC + hoff + dgq * 8;
                vbh = *(const short8*)(gqh + oB);
                vbl = *(const short8*)(gql + oB);
            }
#pragma unroll
            for (int e = 0; e < 8; e++) {
                const int d = dgq * 8 + e;
                const int col = ((kp >> 2) ^ e ^ dgq) & 7;
                const int wo = d * 32 + col * 4 + (kp & 3);
                ((unsigned int*)Vh)[wo] =
                    (unsigned int)(unsigned short)vah[e] | ((unsigned int)(unsigned short)vbh[e] << 16);
                ((unsigned int*)Vl)[wo] =
                    (unsigned int)(unsigned short)vAl[e] | ((unsigned int)(unsigned short)vbl[e] << 16);
            }
        }
        __syncthreads();

        // recompute scores
        f32x4 sc_[4];
#pragma unroll
        for (int t = 0; t < 4; t++) sc_[t] = {0.f, 0.f, 0.f, 0.f};
#pragma unroll
        for (int k32 = 0; k32 < 2; k32++)
#pragma unroll
            for (int t = 0; t < 4; t++) {
                const int pos = (t * 16 + fr) * 64 + ((k32 * 4 + fe) ^ (fr & 7)) * 8;
                const short8 kbh = *(const short8*)&Kh[pos];
                const short8 kbl = *(const short8*)&Kl[pos];
                sc_[t] = __builtin_amdgcn_mfma_f32_16x16x32_bf16(qfh[k32], kbh, sc_[t], 0, 0, 0);
                sc_[t] = __builtin_amdgcn_mfma_f32_16x16x32_bf16(qfl[k32], kbh, sc_[t], 0, 0, 0);
                sc_[t] = __builtin_amdgcn_mfma_f32_16x16x32_bf16(qfh[k32], kbl, sc_[t], 0, 0, 0);
            }

        // finalize weights, write wts, write P to per-wave LDS (transpose)
#pragma unroll
        for (int t = 0; t < 4; t++)
#pragma unroll
            for (int r = 0; r < 4; r++) {
                const int key = ch * 64 + t * 16 + fr;
                float v = sc_[t][r] * 0.125f;
                if (key >= NSEQ) v = -3e38f;
                const bool cls = key < NCLS;
                const float wv = expf(v - (cls ? mc[r] : mp[r])) * (cls ? ic[r] : ip[r]);
                const int q = q0 + fe * 4 + r;
                if (q < NSEQ && key < NSEQ)
                    wts[wbase + (size_t)q * NSEQ + key] = wv;
                Plds[w][(fe * 4 + r) * 68 + t * 16 + fr] = wv;
            }

        // P A-frags (row=lane&15) + PV MFMA
#pragma unroll
        for (int kh2 = 0; kh2 < 2; kh2++) {
            float pv[8];
            *(float4*)&pv[0] = *(const float4*)&Plds[w][fr * 68 + kh2 * 32 + fe * 8];
            *(float4*)&pv[4] = *(const float4*)&Plds[w][fr * 68 + kh2 * 32 + fe * 8 + 4];
            short8 ph, pl;
#pragma unroll
            for (int j = 0; j < 8; j++) {
                const unsigned short hh = bf16_rn(pv[j]);
                ph[j] = (short)hh;
                pl[j] = (short)bf16_rn(pv[j] - bf16_tof(hh));
            }
#pragma unroll
            for (int dt = 0; dt < 4; dt++) {
                const int d = dt * 16 + fr;
                const int col = ((kh2 * 4 + fe) ^ (d & 7) ^ ((d >> 3) & 7)) & 7;
                const short8 vfh = *(const short8*)&Vh[d * 64 + col * 8];
                const short8 vfl = *(const short8*)&Vl[d * 64 + col * 8];
                oacc[dt] = __builtin_amdgcn_mfma_f32_16x16x32_bf16(ph, vfh, oacc[dt], 0, 0, 0);
                oacc[dt] = __builtin_amdgcn_mfma_f32_16x16x32_bf16(pl, vfh, oacc[dt], 0, 0, 0);
                oacc[dt] = __builtin_amdgcn_mfma_f32_16x16x32_bf16(ph, vfl, oacc[dt], 0, 0, 0);
            }
        }
    }

    // ---- O epilogue: hi/lo bf16 for proj GEMM ----
#pragma unroll
    for (int dt = 0; dt < 4; dt++)
#pragma unroll
        for (int r = 0; r < 4; r++) {
            const int q = q0 + fe * 4 + r;
            if (q < NSEQ) {
                const size_t idx = (tokbase + q) * DIMC + hoff + dt * 16 + fr;
                const float v = oacc[dt][r];
                const unsigned short hh = bf16_rn(v);
                oh[idx] = hh;
                ol[idx] = bf16_rn(v - bf16_tof(hh));
            }
        }
}

// ============================================================
// launcher
// ============================================================
extern "C" void kernel_launch(void* const* d_in, const int* in_sizes, int n_in,
                              void* d_out, int out_size, void* d_ws, size_t ws_size,
                              hipStream_t stream) {
    const float* x      = (const float*)d_in[0];
    const float* qkv_w  = (const float*)d_in[1];
    const float* qkv_b  = (const float*)d_in[2];
    const float* proj_w = (const float*)d_in[3];
    const float* proj_b = (const float*)d_in[4];
    const float* ln1_g  = (const float*)d_in[5];
    const float* ln1_b  = (const float*)d_in[6];
    const float* ln2_g  = (const float*)d_in[7];
    const float* ln2_b  = (const float*)d_in[8];
    const float* fc1_w  = (const float*)d_in[9];
    const float* fc1_b  = (const float*)d_in[10];
    const float* fc2_w  = (const float*)d_in[11];
    const float* fc2_b  = (const float*)d_in[12];

    float* out0 = (float*)d_out;                       // [16,596,768]
    float* wts  = out0 + (size_t)NT * DIMC;            // [16,12,596,596]

    // ---- workspace layout ----
    // region A (87.9 MB): qkv hi/lo bf16 [NT][2304] x2 -> later hh hi/lo [MH,3072] x2
    // S region (29.3 MB): hi/lo [NT,768] bf16 (xln -> attn_out -> ln2_out)
    // x1       (29.3 MB): fp32 [NT,768]
    // W region (28.3 MB): weight hi/lo bf16
    char* ws = (char*)d_ws;
    unsigned short* qkv_h = (unsigned short*)ws;
    unsigned short* qkv_l = qkv_h + (size_t)NT * C3;
    unsigned short* hh_h = (unsigned short*)ws;        // overlays qkv (dead by FC1)
    unsigned short* hh_l = hh_h + (size_t)MH * HID;
    char* sReg = ws + (size_t)NT * C3 * 4;
    unsigned short* s_h = (unsigned short*)sReg;
    unsigned short* s_l = s_h + (size_t)NT * DIMC;
    float* x1 = (float*)(sReg + (size_t)NT * DIMC * 4);
    char* wReg = (char*)x1 + (size_t)NT * DIMC * 4;
    unsigned short* qw_h = (unsigned short*)wReg;
    unsigned short* qw_l = qw_h + (size_t)C3 * DIMC;
    unsigned short* pw_h = qw_l + (size_t)C3 * DIMC;
    unsigned short* pw_l = pw_h + (size_t)DIMC * DIMC;
    unsigned short* f1_h = pw_l + (size_t)DIMC * DIMC;
    unsigned short* f1_l = f1_h + (size_t)HID * DIMC;
    unsigned short* f2_h = f1_l + (size_t)HID * DIMC;
    unsigned short* f2_l = f2_h + (size_t)DIMC * HID;

    // 1. LN1 -> hi/lo bf16
    ln_kernel<<<NT, 256, 0, stream>>>(x, ln1_g, ln1_b, s_h, s_l);
    // 1b. weight splits
    split_kernel<<<1024, 256, 0, stream>>>(qkv_w, qw_h, qw_l, C3 * DIMC / 4);
    split_kernel<<<576, 256, 0, stream>>>(proj_w, pw_h, pw_l, DIMC * DIMC / 4);
    split_kernel<<<1024, 256, 0, stream>>>(fc1_w, f1_h, f1_l, HID * DIMC / 4);
    split_kernel<<<1024, 256, 0, stream>>>(fc2_w, f2_h, f2_l, DIMC * HID / 4);
    // 2. QKV GEMM -> qkv hi/lo bf16
    mgemm_kernel<3><<<dim3(C3 / 128, (NT + 127) / 128), 256, 0, stream>>>(
        s_h, s_l, qw_h, qw_l, qkv_b, nullptr, nullptr, qkv_h, qkv_l, NT, C3, DIMC);
    // 3+4. fused attention: wts output + O (hi/lo) in S region (xln dead)
    fattn_kernel<<<dim3(NBATCH * NHEADS, 10), 256, 0, stream>>>(qkv_h, qkv_l, wts, s_h, s_l);
    // 5. proj GEMM + residual(x) -> x1 fp32
    mgemm_kernel<1><<<dim3(DIMC / 128, (NT + 127) / 128), 256, 0, stream>>>(
        s_h, s_l, pw_h, pw_l, proj_b, x, x1, nullptr, nullptr, NT, DIMC, DIMC);
    // 6. LN2 -> hi/lo bf16 in S region (attn_out dead)
    ln_kernel<<<NT, 256, 0, stream>>>(x1, ln2_g, ln2_b, s_h, s_l);
    // 7/8. FC1 (GELU -> hh hi/lo over dead qkv) + FC2 (+residual x1) in M-halves
    for (int hf = 0; hf < 2; hf++) {
        const size_t r0 = (size_t)hf * MH;
        mgemm_kernel<2><<<dim3(HID / 128, (MH + 127) / 128), 256, 0, stream>>>(
            s_h + r0 * DIMC, s_l + r0 * DIMC, f1_h, f1_l, fc1_b, nullptr,
            nullptr, hh_h, hh_l, MH, HID, DIMC);
        mgemm_kernel<1><<<dim3(DIMC / 128, (MH + 127) / 128), 256, 0, stream>>>(
            hh_h, hh_l, f2_h, f2_l, fc2_b, x1 + r0 * DIMC,
            out0 + r0 * DIMC, nullptr, nullptr, MH, DIMC, HID);
    }
}

// Round 6
// 1192.134 us; speedup vs baseline: 2.5020x; 1.0442x over previous
//
#include <hip/hip_runtime.h>
#include <math.h>

// ---- problem constants ----
constexpr int DIMC   = 768;
constexpr int NHEADS = 12;
constexpr int HD     = 64;
constexpr int NCLS   = 20;
constexpr int HID    = 3072;
constexpr int NBATCH = 16;
constexpr int NSEQ   = 596;
constexpr int NT     = NBATCH * NSEQ;   // 9536 tokens
constexpr int C3     = 3 * DIMC;        // 2304
constexpr int MH     = NT / 2;          // 4768 (FC M-split half)
#define LN_EPS 1e-5f

typedef __attribute__((ext_vector_type(8))) short short8;   // 8 bf16 = 4 VGPR
typedef __attribute__((ext_vector_type(4))) float f32x4;

// ---- bf16 helpers (RN) ----
__device__ __forceinline__ unsigned short bf16_rn(float f) {
    unsigned u = __float_as_uint(f);
    u += 0x7fffu + ((u >> 16) & 1u);
    return (unsigned short)(u >> 16);
}
__device__ __forceinline__ float bf16_tof(unsigned short h) {
    return __uint_as_float(((unsigned)h) << 16);
}

__device__ __forceinline__ float gelu_f(float v) {
    return 0.5f * v * (1.0f + erff(v * 0.70710678118654752f));
}

// async global->LDS, 16B per lane, wave-uniform LDS base
typedef __attribute__((address_space(1))) const unsigned int gu32;
typedef __attribute__((address_space(3))) unsigned int lu32;
#define GLOAD16(gp, lp) __builtin_amdgcn_global_load_lds((gu32*)(gp), (lu32*)(lp), 16, 0, 0)

// ============================================================
// split fp32 -> (hi, lo) bf16 arrays. n4 = n/4.
// ============================================================
__global__ __launch_bounds__(256) void split_kernel(const float* __restrict__ in,
                                                    unsigned short* __restrict__ hi,
                                                    unsigned short* __restrict__ lo,
                                                    int n4) {
    int i = blockIdx.x * 256 + threadIdx.x;
    const int stp = gridDim.x * 256;
    for (; i < n4; i += stp) {
        const float4 v = ((const float4*)in)[i];
        ushort4 h, l;
        h.x = bf16_rn(v.x); l.x = bf16_rn(v.x - bf16_tof(h.x));
        h.y = bf16_rn(v.y); l.y = bf16_rn(v.y - bf16_tof(h.y));
        h.z = bf16_rn(v.z); l.z = bf16_rn(v.z - bf16_tof(h.z));
        h.w = bf16_rn(v.w); l.w = bf16_rn(v.w - bf16_tof(h.w));
        ((ushort4*)hi)[i] = h;
        ((ushort4*)lo)[i] = l;
    }
}

// ============================================================
// LayerNorm: one block (256 thr) per row of 768 -> hi/lo bf16 out
// ============================================================
__global__ __launch_bounds__(256) void ln_kernel(const float* __restrict__ x,
                                                 const float* __restrict__ g,
                                                 const float* __restrict__ b,
                                                 unsigned short* __restrict__ yh,
                                                 unsigned short* __restrict__ yl) {
    const int row = blockIdx.x;
    const float* xr = x + (size_t)row * DIMC;
    const int t = threadIdx.x;
    float v0 = xr[t];
    float v1 = xr[t + 256];
    float v2 = xr[t + 512];
    float s  = v0 + v1 + v2;
    float ss = v0 * v0 + v1 * v1 + v2 * v2;
#pragma unroll
    for (int m = 1; m < 64; m <<= 1) {
        s  += __shfl_xor(s, m);
        ss += __shfl_xor(ss, m);
    }
    __shared__ float ls[4], lss[4];
    const int wid = t >> 6;
    if ((t & 63) == 0) { ls[wid] = s; lss[wid] = ss; }
    __syncthreads();
    s  = ls[0] + ls[1] + ls[2] + ls[3];
    ss = lss[0] + lss[1] + lss[2] + lss[3];
    const float mean = s * (1.0f / DIMC);
    const float var  = ss * (1.0f / DIMC) - mean * mean;
    const float rstd = rsqrtf(var + LN_EPS);
    const size_t base = (size_t)row * DIMC;
#pragma unroll
    for (int e = 0; e < 3; e++) {
        const int c = t + e * 256;
        const float v = (e == 0) ? v0 : (e == 1) ? v1 : v2;
        const float y = (v - mean) * rstd * g[c] + b[c];
        const unsigned short h = bf16_rn(y);
        yh[base + c] = h;
        yl[base + c] = bf16_rn(y - bf16_tof(h));
    }
}

// ============================================================
// MFMA GEMM v2 (bf16x3): Out[M,N] = A[M,K] @ W[N,K]^T + bias (+res | gelu)
// A,W as hi bf16 base + lo at element offset (AloOff/WloOff).
// 128x128 tile, BK=32, 4 waves (2x2). Double-buffered LDS, stage-early,
// ONE __syncthreads per K-step:
//   STAGE(buf0,0); loop t: { barrier; STAGE(buf[t+1], t+1); compute(buf[t]); }
// Barrier's implicit vmcnt(0)/lgkmcnt(0) drain (a) confirms stage(t)
// landed, (b) orders all waves' compute(t-1) ds_reads before buf[t+1] is
// overwritten -> race-free with one barrier; loads fly during MFMA.
// LDS row = 128B: slot s of row r holds (u = s^(r&7)): u<4 -> hi chunk u,
// u>=4 -> lo chunk u&3. Wave wid stages rows wid*32+i*8+(lane>>3) to LDS
// base (wid*4+i)*512 (lane l -> row +l>>3, slot l&7).   [r5 bug: wid was
// dropped -> 3/4 of LDS never written -> NaN. Fixed.]
// Read slot hi: fe^(r&7), lo: (fe^4)^(r&7) -> conflict-free.
// Bijective XCD swizzle (m204) on the linearized grid.
// EPI: 0 bias->f32, 1 bias+res->f32, 2 bias+GELU->hi/lo, 3 bias->hi/lo
// ============================================================
template <int EPI>
__global__ __launch_bounds__(256) void mgemm_kernel(
    const unsigned short* __restrict__ Ah, const unsigned short* __restrict__ Wh,
    int AloOff, int WloOff,
    const float* __restrict__ bias, const float* __restrict__ res,
    float* __restrict__ Out, unsigned short* __restrict__ OutH,
    unsigned short* __restrict__ OutL, int M, int N, int K)
{
    __shared__ unsigned short S[2][2][128 * 64];   // [buf][A/W][row*64 + slot*8 + e] = 64 KB

    const int tid  = threadIdx.x;
    const int lane = tid & 63, wid = tid >> 6;

    // ---- bijective XCD swizzle (m204) on linearized grid ----
    const int gx = N >> 7;
    const int nb = gridDim.x;
    const int qq = nb >> 3, rr = nb & 7;
    const int xcd = blockIdx.x & 7, bix = blockIdx.x >> 3;
    const int swz = (xcd < rr ? xcd * (qq + 1) : rr * (qq + 1) + (xcd - rr) * qq) + bix;
    const int m0 = (swz / gx) * 128, n0 = (swz % gx) * 128;
    const int wr = wid >> 1, wc = wid & 1;

    // ---- staging per-lane source offsets (element units, k-invariant) ----
    size_t goffA[4], goffW[4];
    int ldsoff[4];
#pragma unroll
    for (int i = 0; i < 4; i++) {
        const int rloc = wid * 32 + i * 8 + (lane >> 3);
        const int u = (lane & 7) ^ (rloc & 7);
        const int chunk = u & 3, isLo = u >> 2;
        goffA[i] = (size_t)(m0 + rloc) * K + chunk * 8 + (isLo ? AloOff : 0);
        goffW[i] = (size_t)(n0 + rloc) * K + chunk * 8 + (isLo ? WloOff : 0);
        ldsoff[i] = (wid * 4 + i) * 512;
    }

    // ---- fragment read offsets (k-invariant) ----
    const int fr = lane & 15, fe = lane >> 4;
    int offAhi[4], offAlo[4], offWhi[4], offWlo[4];
#pragma unroll
    for (int i = 0; i < 4; i++) {
        const int ra = wr * 64 + i * 16 + fr;
        const int rw = wc * 64 + i * 16 + fr;
        offAhi[i] = ra * 64 + (fe ^ (ra & 7)) * 8;
        offAlo[i] = ra * 64 + ((fe ^ 4) ^ (ra & 7)) * 8;
        offWhi[i] = rw * 64 + (fe ^ (rw & 7)) * 8;
        offWlo[i] = rw * 64 + ((fe ^ 4) ^ (rw & 7)) * 8;
    }

    f32x4 acc[4][4];
#pragma unroll
    for (int i = 0; i < 4; i++)
#pragma unroll
        for (int j = 0; j < 4; j++) acc[i][j] = {0.f, 0.f, 0.f, 0.f};

    const int nt = K >> 5;
    // prologue: stage tile 0 into buf 0
#pragma unroll
    for (int i = 0; i < 4; i++) {
        GLOAD16(Ah + goffA[i], &S[0][0][ldsoff[i]]);
        GLOAD16(Wh + goffW[i], &S[0][1][ldsoff[i]]);
    }

    for (int t = 0; t < nt; t++) {
        __syncthreads();   // vmcnt(0): stage(t) landed; all waves past compute(t-1)
        if (t + 1 < nt) {
            const int nxt = (t + 1) & 1;
            const size_t ka = (size_t)(t + 1) << 5;
#pragma unroll
            for (int i = 0; i < 4; i++) {
                GLOAD16(Ah + goffA[i] + ka, &S[nxt][0][ldsoff[i]]);
                GLOAD16(Wh + goffW[i] + ka, &S[nxt][1][ldsoff[i]]);
            }
        }
        const unsigned short* sA = &S[t & 1][0][0];
        const unsigned short* sW = &S[t & 1][1][0];
        short8 a_h[4], a_l[4], w_h[4], w_l[4];
#pragma unroll
        for (int i = 0; i < 4; i++) {
            a_h[i] = *(const short8*)&sA[offAhi[i]];
            a_l[i] = *(const short8*)&sA[offAlo[i]];
            w_h[i] = *(const short8*)&sW[offWhi[i]];
            w_l[i] = *(const short8*)&sW[offWlo[i]];
        }
#pragma unroll
        for (int i = 0; i < 4; i++)
#pragma unroll
            for (int j = 0; j < 4; j++) {
                acc[i][j] = __builtin_amdgcn_mfma_f32_16x16x32_bf16(a_h[i], w_h[j], acc[i][j], 0, 0, 0);
                acc[i][j] = __builtin_amdgcn_mfma_f32_16x16x32_bf16(a_l[i], w_h[j], acc[i][j], 0, 0, 0);
                acc[i][j] = __builtin_amdgcn_mfma_f32_16x16x32_bf16(a_h[i], w_l[j], acc[i][j], 0, 0, 0);
            }
    }

    // ---- epilogue: C/D layout col=lane&15, row=(lane>>4)*4+q ----
#pragma unroll
    for (int j = 0; j < 4; j++) {
        const int col = n0 + wc * 64 + j * 16 + fr;
        const float bj = bias[col];
#pragma unroll
        for (int i = 0; i < 4; i++) {
            const int row0 = m0 + wr * 64 + i * 16 + fe * 4;
#pragma unroll
            for (int q = 0; q < 4; q++) {
                const int gm = row0 + q;
                if (gm < M) {
                    const size_t idx = (size_t)gm * N + col;
                    float v = acc[i][j][q] + bj;
                    if (EPI == 1) v += res[idx];
                    if (EPI == 2) {
                        v = gelu_f(v);
                        const unsigned short hh = bf16_rn(v);
                        OutH[idx] = hh;
                        OutL[idx] = bf16_rn(v - bf16_tof(hh));
                    } else if (EPI == 3) {
                        const unsigned short hh = bf16_rn(v);
                        OutH[idx] = hh;
                        OutL[idx] = bf16_rn(v - bf16_tof(hh));
                    } else {
                        Out[idx] = v;
                    }
                }
            }
        }
    }
}

// ============================================================
// Fused MFMA attention (bf16x3) — unchanged from round 4 (verified).
// ============================================================
__global__ __launch_bounds__(256) void fattn_kernel(
    const unsigned short* __restrict__ gqh, const unsigned short* __restrict__ gql,
    float* __restrict__ wts,
    unsigned short* __restrict__ oh, unsigned short* __restrict__ ol)
{
    __shared__ unsigned short Kh[4096], Kl[4096];   // [64 key][64 d], chunk^=(row&7)
    __shared__ unsigned short Vh[4096], Vl[4096];   // [64 d][64 key], chunk^=(d&7)^(d>>3)
    __shared__ float Plds[4][16 * 68];              // per-wave P transpose

    const int tid = threadIdx.x;
    const int lane = tid & 63, w = tid >> 6;
    const int fr = lane & 15, fe = lane >> 4;
    const int bh = blockIdx.x;
    const int b = bh / NHEADS, h = bh - b * NHEADS;
    const int q0 = blockIdx.y * 64 + w * 16;
    const size_t tokbase = (size_t)b * NSEQ;
    const size_t hoff = (size_t)h * HD;
    const size_t wbase = (size_t)bh * NSEQ * NSEQ;

    short8 qfh[2], qfl[2];
    {
        const short8 z8 = {0, 0, 0, 0, 0, 0, 0, 0};
        qfh[0] = z8; qfh[1] = z8; qfl[0] = z8; qfl[1] = z8;
        const int qi = q0 + fr;
        if (qi < NSEQ) {
            const size_t base = (tokbase + qi) * C3 + hoff + fe * 8;
            qfh[0] = *(const short8*)(gqh + base);
            qfh[1] = *(const short8*)(gqh + base + 32);
            qfl[0] = *(const short8*)(gql + base);
            qfl[1] = *(const short8*)(gql + base + 32);
        }
    }

    const int srow = lane >> 3;
    const int sc8 = (lane & 7) ^ srow;

    float mc[4], mp[4], lc[4], lp[4];
#pragma unroll
    for (int r = 0; r < 4; r++) { mc[r] = -3e38f; mp[r] = -3e38f; lc[r] = 0.f; lp[r] = 0.f; }

    // ================= pass 1: online max+sum =================
    for (int ch = 0; ch < 10; ch++) {
        __syncthreads();
#pragma unroll
        for (int i = 0; i < 2; i++) {
            const int s = w + i * 4;
            const int key = min(ch * 64 + s * 8 + srow, NSEQ - 1);
            const size_t src = (tokbase + key) * C3 + DIMC + hoff + sc8 * 8;
            GLOAD16(gqh + src, &Kh[s * 512]);
            GLOAD16(gql + src, &Kl[s * 512]);
        }
        __syncthreads();

        f32x4 sc_[4];
#pragma unroll
        for (int t = 0; t < 4; t++) sc_[t] = {0.f, 0.f, 0.f, 0.f};
#pragma unroll
        for (int k32 = 0; k32 < 2; k32++)
#pragma unroll
            for (int t = 0; t < 4; t++) {
                const int pos = (t * 16 + fr) * 64 + ((k32 * 4 + fe) ^ (fr & 7)) * 8;
                const short8 kbh = *(const short8*)&Kh[pos];
                const short8 kbl = *(const short8*)&Kl[pos];
                sc_[t] = __builtin_amdgcn_mfma_f32_16x16x32_bf16(qfh[k32], kbh, sc_[t], 0, 0, 0);
                sc_[t] = __builtin_amdgcn_mfma_f32_16x16x32_bf16(qfl[k32], kbh, sc_[t], 0, 0, 0);
                sc_[t] = __builtin_amdgcn_mfma_f32_16x16x32_bf16(qfh[k32], kbl, sc_[t], 0, 0, 0);
            }

        float sv[4][4];
#pragma unroll
        for (int t = 0; t < 4; t++)
#pragma unroll
            for (int r = 0; r < 4; r++) {
                float v = sc_[t][r] * 0.125f;
                if (ch * 64 + t * 16 + fr >= NSEQ) v = -3e38f;
                sv[t][r] = v;
            }

        if (ch == 0) {
#pragma unroll
            for (int r = 0; r < 4; r++) {
                float xc = -3e38f, xp = -3e38f;
#pragma unroll
                for (int t = 0; t < 4; t++) {
                    const bool cls = (t == 0) || (t == 1 && fr < 4);
                    if (cls) xc = fmaxf(xc, sv[t][r]); else xp = fmaxf(xp, sv[t][r]);
                }
#pragma unroll
                for (int o = 1; o < 16; o <<= 1) {
                    xc = fmaxf(xc, __shfl_xor(xc, o));
                    xp = fmaxf(xp, __shfl_xor(xp, o));
                }
                const float mcn = fmaxf(mc[r], xc), mpn = fmaxf(mp[r], xp);
                float ec = 0.f, ep = 0.f;
#pragma unroll
                for (int t = 0; t < 4; t++) {
                    const bool cls = (t == 0) || (t == 1 && fr < 4);
                    const float e = expf(sv[t][r] - (cls ? mcn : mpn));
                    if (cls) ec += e; else ep += e;
                }
#pragma unroll
                for (int o = 1; o < 16; o <<= 1) {
                    ec += __shfl_xor(ec, o);
                    ep += __shfl_xor(ep, o);
                }
                lc[r] = lc[r] * expf(mc[r] - mcn) + ec;
                lp[r] = lp[r] * expf(mp[r] - mpn) + ep;
                mc[r] = mcn; mp[r] = mpn;
            }
        } else {
#pragma unroll
            for (int r = 0; r < 4; r++) {
                float xp = fmaxf(fmaxf(sv[0][r], sv[1][r]), fmaxf(sv[2][r], sv[3][r]));
#pragma unroll
                for (int o = 1; o < 16; o <<= 1) xp = fmaxf(xp, __shfl_xor(xp, o));
                const float mpn = fmaxf(mp[r], xp);
                float ep = 0.f;
#pragma unroll
                for (int t = 0; t < 4; t++) ep += expf(sv[t][r] - mpn);
#pragma unroll
                for (int o = 1; o < 16; o <<= 1) ep += __shfl_xor(ep, o);
                lp[r] = lp[r] * expf(mp[r] - mpn) + ep;
                mp[r] = mpn;
            }
        }
    }

    float ic[4], ip[4];
#pragma unroll
    for (int r = 0; r < 4; r++) { ic[r] = 1.f / lc[r]; ip[r] = 1.f / lp[r]; }

    // ================= pass 2: wts + PV =================
    f32x4 oacc[4];
#pragma unroll
    for (int dt = 0; dt < 4; dt++) oacc[dt] = {0.f, 0.f, 0.f, 0.f};

    const int dgq = tid & 7;
    const int kp  = tid >> 3;

    for (int ch = 0; ch < 10; ch++) {
        __syncthreads();
#pragma unroll
        for (int i = 0; i < 2; i++) {
            const int s = w + i * 4;
            const int key = min(ch * 64 + s * 8 + srow, NSEQ - 1);
            const size_t src = (tokbase + key) * C3 + DIMC + hoff + sc8 * 8;
            GLOAD16(gqh + src, &Kh[s * 512]);
            GLOAD16(gql + src, &Kl[s * 512]);
        }
        {
            const short8 z8 = {0, 0, 0, 0, 0, 0, 0, 0};
            short8 vah = z8, vAl = z8, vbh = z8, vbl = z8;
            const int keyA = ch * 64 + kp * 2;
            if (keyA < NSEQ) {
                const size_t oA = (tokbase + keyA) * C3 + 2 * DIMC + hoff + dgq * 8;
                vah = *(const short8*)(gqh + oA);
                vAl = *(const short8*)(gql + oA);
            }
            if (keyA + 1 < NSEQ) {
                const size_t oB = (tokbase + keyA + 1) * C3 + 2 * DIMC + hoff + dgq * 8;
                vbh = *(const short8*)(gqh + oB);
                vbl = *(const short8*)(gql + oB);
            }
#pragma unroll
            for (int e = 0; e < 8; e++) {
                const int d = dgq * 8 + e;
                const int col = ((kp >> 2) ^ e ^ dgq) & 7;
                const int wo = d * 32 + col * 4 + (kp & 3);
                ((unsigned int*)Vh)[wo] =
                    (unsigned int)(unsigned short)vah[e] | ((unsigned int)(unsigned short)vbh[e] << 16);
                ((unsigned int*)Vl)[wo] =
                    (unsigned int)(unsigned short)vAl[e] | ((unsigned int)(unsigned short)vbl[e] << 16);
            }
        }
        __syncthreads();

        f32x4 sc_[4];
#pragma unroll
        for (int t = 0; t < 4; t++) sc_[t] = {0.f, 0.f, 0.f, 0.f};
#pragma unroll
        for (int k32 = 0; k32 < 2; k32++)
#pragma unroll
            for (int t = 0; t < 4; t++) {
                const int pos = (t * 16 + fr) * 64 + ((k32 * 4 + fe) ^ (fr & 7)) * 8;
                const short8 kbh = *(const short8*)&Kh[pos];
                const short8 kbl = *(const short8*)&Kl[pos];
                sc_[t] = __builtin_amdgcn_mfma_f32_16x16x32_bf16(qfh[k32], kbh, sc_[t], 0, 0, 0);
                sc_[t] = __builtin_amdgcn_mfma_f32_16x16x32_bf16(qfl[k32], kbh, sc_[t], 0, 0, 0);
                sc_[t] = __builtin_amdgcn_mfma_f32_16x16x32_bf16(qfh[k32], kbl, sc_[t], 0, 0, 0);
            }

#pragma unroll
        for (int t = 0; t < 4; t++)
#pragma unroll
            for (int r = 0; r < 4; r++) {
                const int key = ch * 64 + t * 16 + fr;
                float v = sc_[t][r] * 0.125f;
                if (key >= NSEQ) v = -3e38f;
                const bool cls = key < NCLS;
                const float wv = expf(v - (cls ? mc[r] : mp[r])) * (cls ? ic[r] : ip[r]);
                const int q = q0 + fe * 4 + r;
                if (q < NSEQ && key < NSEQ)
                    wts[wbase + (size_t)q * NSEQ + key] = wv;
                Plds[w][(fe * 4 + r) * 68 + t * 16 + fr] = wv;
            }

#pragma unroll
        for (int kh2 = 0; kh2 < 2; kh2++) {
            float pv[8];
            *(float4*)&pv[0] = *(const float4*)&Plds[w][fr * 68 + kh2 * 32 + fe * 8];
            *(float4*)&pv[4] = *(const float4*)&Plds[w][fr * 68 + kh2 * 32 + fe * 8 + 4];
            short8 ph, pl;
#pragma unroll
            for (int j = 0; j < 8; j++) {
                const unsigned short hh = bf16_rn(pv[j]);
                ph[j] = (short)hh;
                pl[j] = (short)bf16_rn(pv[j] - bf16_tof(hh));
            }
#pragma unroll
            for (int dt = 0; dt < 4; dt++) {
                const int d = dt * 16 + fr;
                const int col = ((kh2 * 4 + fe) ^ (d & 7) ^ ((d >> 3) & 7)) & 7;
                const short8 vfh = *(const short8*)&Vh[d * 64 + col * 8];
                const short8 vfl = *(const short8*)&Vl[d * 64 + col * 8];
                oacc[dt] = __builtin_amdgcn_mfma_f32_16x16x32_bf16(ph, vfh, oacc[dt], 0, 0, 0);
                oacc[dt] = __builtin_amdgcn_mfma_f32_16x16x32_bf16(pl, vfh, oacc[dt], 0, 0, 0);
                oacc[dt] = __builtin_amdgcn_mfma_f32_16x16x32_bf16(ph, vfl, oacc[dt], 0, 0, 0);
            }
        }
    }

#pragma unroll
    for (int dt = 0; dt < 4; dt++)
#pragma unroll
        for (int r = 0; r < 4; r++) {
            const int q = q0 + fe * 4 + r;
            if (q < NSEQ) {
                const size_t idx = (tokbase + q) * DIMC + hoff + dt * 16 + fr;
                const float v = oacc[dt][r];
                const unsigned short hh = bf16_rn(v);
                oh[idx] = hh;
                ol[idx] = bf16_tof(hh) == v ? 0 : bf16_rn(v - bf16_tof(hh));
            }
        }
}

// ============================================================
// launcher
// ============================================================
extern "C" void kernel_launch(void* const* d_in, const int* in_sizes, int n_in,
                              void* d_out, int out_size, void* d_ws, size_t ws_size,
                              hipStream_t stream) {
    const float* x      = (const float*)d_in[0];
    const float* qkv_w  = (const float*)d_in[1];
    const float* qkv_b  = (const float*)d_in[2];
    const float* proj_w = (const float*)d_in[3];
    const float* proj_b = (const float*)d_in[4];
    const float* ln1_g  = (const float*)d_in[5];
    const float* ln1_b  = (const float*)d_in[6];
    const float* ln2_g  = (const float*)d_in[7];
    const float* ln2_b  = (const float*)d_in[8];
    const float* fc1_w  = (const float*)d_in[9];
    const float* fc1_b  = (const float*)d_in[10];
    const float* fc2_w  = (const float*)d_in[11];
    const float* fc2_b  = (const float*)d_in[12];

    float* out0 = (float*)d_out;                       // [16,596,768]
    float* wts  = out0 + (size_t)NT * DIMC;            // [16,12,596,596]

    // ---- workspace layout ----
    char* ws = (char*)d_ws;
    unsigned short* qkv_h = (unsigned short*)ws;
    unsigned short* qkv_l = qkv_h + (size_t)NT * C3;
    unsigned short* hh_h = (unsigned short*)ws;        // overlays qkv (dead by FC1)
    unsigned short* hh_l = hh_h + (size_t)MH * HID;
    char* sReg = ws + (size_t)NT * C3 * 4;
    unsigned short* s_h = (unsigned short*)sReg;
    unsigned short* s_l = s_h + (size_t)NT * DIMC;
    float* x1 = (float*)(sReg + (size_t)NT * DIMC * 4);
    char* wReg = (char*)x1 + (size_t)NT * DIMC * 4;
    unsigned short* qw_h = (unsigned short*)wReg;
    unsigned short* qw_l = qw_h + (size_t)C3 * DIMC;
    unsigned short* pw_h = qw_l + (size_t)C3 * DIMC;
    unsigned short* pw_l = pw_h + (size_t)DIMC * DIMC;
    unsigned short* f1_h = pw_l + (size_t)DIMC * DIMC;
    unsigned short* f1_l = f1_h + (size_t)HID * DIMC;
    unsigned short* f2_h = f1_l + (size_t)HID * DIMC;
    unsigned short* f2_l = f2_h + (size_t)DIMC * HID;

    // 1. LN1 -> hi/lo bf16
    ln_kernel<<<NT, 256, 0, stream>>>(x, ln1_g, ln1_b, s_h, s_l);
    // 1b. weight splits
    split_kernel<<<1024, 256, 0, stream>>>(qkv_w, qw_h, qw_l, C3 * DIMC / 4);
    split_kernel<<<576, 256, 0, stream>>>(proj_w, pw_h, pw_l, DIMC * DIMC / 4);
    split_kernel<<<1024, 256, 0, stream>>>(fc1_w, f1_h, f1_l, HID * DIMC / 4);
    split_kernel<<<1024, 256, 0, stream>>>(fc2_w, f2_h, f2_l, DIMC * HID / 4);
    // 2. QKV GEMM -> qkv hi/lo bf16
    mgemm_kernel<3><<<(C3 / 128) * ((NT + 127) / 128), 256, 0, stream>>>(
        s_h, qw_h, NT * DIMC, C3 * DIMC, qkv_b, nullptr,
        nullptr, qkv_h, qkv_l, NT, C3, DIMC);
    // 3+4. fused attention: wts output + O (hi/lo) in S region (xln dead)
    fattn_kernel<<<dim3(NBATCH * NHEADS, 10), 256, 0, stream>>>(qkv_h, qkv_l, wts, s_h, s_l);
    // 5. proj GEMM + residual(x) -> x1 fp32
    mgemm_kernel<1><<<(DIMC / 128) * ((NT + 127) / 128), 256, 0, stream>>>(
        s_h, pw_h, NT * DIMC, DIMC * DIMC, proj_b, x,
        x1, nullptr, nullptr, NT, DIMC, DIMC);
    // 6. LN2 -> hi/lo bf16 in S region (attn_out dead)
    ln_kernel<<<NT, 256, 0, stream>>>(x1, ln2_g, ln2_b, s_h, s_l);
    // 7/8. FC1 (GELU -> hh hi/lo over dead qkv) + FC2 (+residual x1) in M-halves
    for (int hf = 0; hf < 2; hf++) {
        const size_t r0 = (size_t)hf * MH;
        mgemm_kernel<2><<<(HID / 128) * ((MH + 127) / 128), 256, 0, stream>>>(
            s_h + r0 * DIMC, f1_h, NT * DIMC, HID * DIMC, fc1_b, nullptr,
            nullptr, hh_h, hh_l, MH, HID, DIMC);
        mgemm_kernel<1><<<(DIMC / 128) * ((MH + 127) / 128), 256, 0, stream>>>(
            hh_h, f2_h, MH * HID, DIMC * HID, fc2_b, x1 + r0 * DIMC,
            out0 + r0 * DIMC, nullptr, nullptr, MH, DIMC, HID);
    }
}